// Round 3
// baseline (631.050 us; speedup 1.0000x reference)
//
#include <hip/hip_runtime.h>
#include <math.h>

// Problem constants
constexpr int kB    = 64;
constexpr int kN    = 32;
constexpr int kDIN  = 128;
constexpr int kH    = 256;
constexpr int kG4   = 1024;   // 4*H
constexpr int kDOUT = 128;
constexpr int kBN   = 2048;   // B*N

typedef __attribute__((ext_vector_type(8))) short bf16x8;
typedef __attribute__((ext_vector_type(4))) float f32x4;

// fast sigmoid/tanh: v_exp_f32 + v_rcp_f32 (1-2 ulp, far below bf16-h noise)
__device__ __forceinline__ float sigm(float x) {
    return __builtin_amdgcn_rcpf(1.0f + __expf(-x));
}
__device__ __forceinline__ float tanh_f(float x) {
    return 1.0f - 2.0f * __builtin_amdgcn_rcpf(1.0f + __expf(2.0f * x));
}

// fp32 -> bf16 bits, round-to-nearest-even
__device__ __forceinline__ short f2bf(float f) {
    union { float f; unsigned u; } v; v.f = f;
    unsigned r = v.u + 0x7fffu + ((v.u >> 16) & 1u);
    return (short)(r >> 16);
}

// ---------------------------------------------------------------------------
// prep:
//   [0,128)   transpose W_ih_f (1024x128) -> WihT_f [k][gate]
//   [128,256) transpose W_ih_r            -> WihT_r
//   [256,320) transpose W_fc   (128x512)  -> WfcT   [k][dout]
//   [320,448) pack W_hh (bf16) into per-wave MFMA fragment order:
//             Wp[((w*8+kt)*8+tau)*512 + lane*8 + j]
//               = W_hh[nb(w,tau)+l15][kt*32+quad*8+j]
//   [448,456) transpose mask -> mask_t [n][t][b]
// ---------------------------------------------------------------------------
__global__ __launch_bounds__(256) void prep_k(
    const float* __restrict__ Wihf, const float* __restrict__ Wihr,
    const float* __restrict__ Whhf, const float* __restrict__ Whhr,
    const float* __restrict__ Wfc,  const float* __restrict__ mask,
    float* __restrict__ WihTf, float* __restrict__ WihTr,
    float* __restrict__ WfcT,  float* __restrict__ mask_t,
    short* __restrict__ Wp_f,  short* __restrict__ Wp_r)
{
    const int bx  = blockIdx.x;
    const int tid = threadIdx.y * 32 + threadIdx.x;

    if (bx >= 448) {                       // mask transpose: [b][n][t] -> [n][t][b]
        const int base = (bx - 448) * 8192 + tid;
        #pragma unroll
        for (int i = 0; i < 32; ++i) {
            const int idx = base + i * 256;
            const int n = idx >> 11, tt = (idx >> 6) & 31, b = idx & 63;
            mask_t[idx] = mask[(size_t)b * 1024 + n * 32 + tt];
        }
        return;
    }
    if (bx >= 320) {                       // W_hh fragment pack
        const int idx = bx - 320;
        const int dir = idx >> 6;
        const int wv  = (idx >> 3) & 7;
        const int kt  = idx & 7;
        const float* src = dir ? Whhr : Whhf;
        short* dst = (dir ? Wp_r : Wp_f) + (size_t)((wv * 8 + kt) * 8) * 512;
        for (int i = tid; i < 512; i += 256) {
            const int tau = i >> 6, lane = i & 63;
            const int qd = lane >> 4, l = lane & 15;
            const int gate = (tau >> 1) * 256 + wv * 32 + (tau & 1) * 16 + l;
            const int ks = kt * 32 + qd * 8;
            bf16x8 v;
            #pragma unroll
            for (int j = 0; j < 8; ++j) v[j] = f2bf(src[(size_t)gate * kH + ks + j]);
            *(bf16x8*)(dst + tau * 512 + lane * 8) = v;
        }
        return;
    }
    __shared__ float tile[32][33];
    const float* src; float* dst; int R, C, t;
    if (bx < 128)      { src = Wihf; dst = WihTf; R = 1024; C = 128; t = bx; }
    else if (bx < 256) { src = Wihr; dst = WihTr; R = 1024; C = 128; t = bx - 128; }
    else               { src = Wfc;  dst = WfcT;  R = 128;  C = 512; t = bx - 256; }
    const int tilesX = C / 32;
    const int c0 = (t % tilesX) * 32;
    const int r0 = (t / tilesX) * 32;
    const int tx = threadIdx.x, ty = threadIdx.y;
    #pragma unroll
    for (int i = ty; i < 32; i += 8)
        tile[i][tx] = src[(size_t)(r0 + i) * C + (c0 + tx)];
    __syncthreads();
    #pragma unroll
    for (int i = ty; i < 32; i += 8)
        dst[(size_t)(c0 + i) * R + (r0 + tx)] = tile[tx][i];
}

// ---------------------------------------------------------------------------
// k1: xW = x @ W_ih.T, written in k2's packed-fragment layout (M=16 tiles):
//   xWP[(t*4+bq4)*4096 + w*512 + tau*64 + qd*16 + l15]  (f32x4 over r)
//     = xW(b = bq4*16 + qd*4 + r, gate = nb(w,tau)+l15)
// Grid 128 = dir(2) x t(32) x bq(2: 32 rows) -> W_ih streamed once per
// 32 rows (66 MB total, half of before). 512 thr; 8-row x 8-gate reg tile.
// ---------------------------------------------------------------------------
__global__ __launch_bounds__(512) void k1_xw(
    const float* __restrict__ x,
    const float* __restrict__ WihT_f, const float* __restrict__ WihT_r,
    float* __restrict__ xWP_f, float* __restrict__ xWP_r)
{
    __shared__ float xs[32][128];               // 16 KB
    const int tid  = threadIdx.x;
    const int bx   = blockIdx.x;
    const int dir  = bx >> 6;
    const int rest = bx & 63;
    const int t    = rest >> 1;
    const int bq   = rest & 1;                  // 32-batch half
    const float* __restrict__ WT = dir ? WihT_r : WihT_f;
    float* __restrict__ xWP = dir ? xWP_r : xWP_f;

    for (int i = tid; i < 1024; i += 512) {
        const int rr = i >> 5, c4 = i & 31;
        *(f32x4*)&xs[rr][c4 * 4] =
            *(const f32x4*)&x[((size_t)(bq * 32 + rr) * 32 + t) * 128 + c4 * 4];
    }
    __syncthreads();

    const int rowg = tid >> 7;    // 0..3 -> rows rowg*8..+7
    const int gg   = tid & 127;   // gates {gg*4+j} and {512+gg*4+j}

    float acc0[8][4], acc1[8][4];
    #pragma unroll
    for (int r = 0; r < 8; ++r)
        #pragma unroll
        for (int j = 0; j < 4; ++j) { acc0[r][j] = 0.f; acc1[r][j] = 0.f; }

    for (int k4 = 0; k4 < 32; ++k4) {
        f32x4 w0[4], w1[4], xv[8];
        #pragma unroll
        for (int kk = 0; kk < 4; ++kk) {
            w0[kk] = *(const f32x4*)&WT[(size_t)(k4 * 4 + kk) * 1024 + gg * 4];
            w1[kk] = *(const f32x4*)&WT[(size_t)(k4 * 4 + kk) * 1024 + 512 + gg * 4];
        }
        #pragma unroll
        for (int r = 0; r < 8; ++r) xv[r] = *(const f32x4*)&xs[rowg * 8 + r][k4 * 4];
        #pragma unroll
        for (int r = 0; r < 8; ++r)
            #pragma unroll
            for (int kk = 0; kk < 4; ++kk) {
                const float xk = xv[r][kk];
                #pragma unroll
                for (int j = 0; j < 4; ++j) {
                    acc0[r][j] = fmaf(xk, w0[kk][j], acc0[r][j]);
                    acc1[r][j] = fmaf(xk, w1[kk][j], acc1[r][j]);
                }
            }
    }

    #pragma unroll
    for (int hf = 0; hf < 2; ++hf)
        #pragma unroll
        for (int j = 0; j < 4; ++j) {
            const int g    = hf * 512 + gg * 4 + j;
            const int l15g = g & 15;
            const int qg   = (g >> 4) & 1;
            const int wg   = (g >> 5) & 7;
            const int taug = (g >> 8) * 2 + qg;
            #pragma unroll
            for (int p = 0; p < 2; ++p) {
                const int b   = bq * 32 + rowg * 8 + p * 4;   // +r in vector
                const int bq4 = b >> 4;
                const int qd  = (b >> 2) & 3;
                f32x4 v;
                #pragma unroll
                for (int r = 0; r < 4; ++r)
                    v[r] = hf ? acc1[p * 4 + r][j] : acc0[p * 4 + r][j];
                ((f32x4*)xWP)[(size_t)(t * 4 + bq4) * 4096 + wg * 512 + taug * 64
                              + qd * 16 + l15g] = v;
            }
        }
}

// ---------------------------------------------------------------------------
// k2: bidirectional LSTM recurrence, bf16 MFMA fp32 accumulate.
// Grid 128 = dir(2) x n(32) x bh(2: 32 batches). 512 thr = 8 waves, M=32.
// Rationale: W stream per block-step (512 KB) is M-invariant, so M=32 halves
// total L2 W traffic vs M=16 and doubles MFMA work per W byte.
// One-step-deep register prefetch of packed xW+mask (proven in r0/r2).
// No __launch_bounds__ min-waves: full 256-VGPR budget for load pipelining.
// h_lds row stride 264 shorts (bank-stride 4): conflict-neutral b128 reads.
// ---------------------------------------------------------------------------
__global__ __launch_bounds__(512) void k2_lstm(
    const float* __restrict__ mask_t,
    const float* __restrict__ xWP_f, const float* __restrict__ xWP_r,
    const short* __restrict__ Wp_f, const short* __restrict__ Wp_r,
    const float* __restrict__ b_f,  const float* __restrict__ b_r,
    float* __restrict__ y)
{
    constexpr int HP = 264;
    __shared__ short h_lds[2][32][HP];          // 33 KB

    const int tid  = threadIdx.x;
    const int w    = tid >> 6;
    const int lane = tid & 63;
    const int quad = lane >> 4;
    const int l15  = lane & 15;

    const int bx    = blockIdx.x;
    const int dir   = bx >> 6;                  // 0 fwd, 1 rev
    const int rest  = bx & 63;
    const int n_seq = rest >> 1;                // 0..31
    const int bh    = rest & 1;                 // 32-batch half

    const float* __restrict__ xWP = dir ? xWP_r : xWP_f;
    const short* __restrict__ Wp  = dir ? Wp_r  : Wp_f;
    const float* __restrict__ bb  = dir ? b_r   : b_f;

    float bias[8];
    #pragma unroll
    for (int g = 0; g < 4; ++g)
        #pragma unroll
        for (int q = 0; q < 2; ++q)
            bias[g * 2 + q] = bb[g * 256 + w * 32 + q * 16 + l15];

    const short* wbase = Wp + (size_t)w * 8 * 8 * 512 + lane * 8;

    float c[16];
    #pragma unroll
    for (int i = 0; i < 16; ++i) c[i] = 0.f;

    const int nsteps = dir ? (kN - n_seq) : (n_seq + 1);
    const int t0     = dir ? (kN - 1) : 0;

    // initial prefetch of packed xW + mask for t0
    f32x4 xwn[8][2];
    f32x4 mkn[2];
    {
        const f32x4* xb4 = (const f32x4*)xWP
            + ((size_t)(t0 * 4 + bh * 2) * 4096 + w * 512 + lane);
        #pragma unroll
        for (int tau = 0; tau < 8; ++tau)
            #pragma unroll
            for (int Mt = 0; Mt < 2; ++Mt)
                xwn[tau][Mt] = xb4[Mt * 4096 + tau * 64];
        #pragma unroll
        for (int Mt = 0; Mt < 2; ++Mt)
            mkn[Mt] = ((const f32x4*)mask_t)[(n_seq * 32 + t0) * 16
                                             + bh * 8 + Mt * 4 + quad];
    }

    int cur = 0;
    for (int it = 0; it < nsteps; ++it) {
        const int t = dir ? (kN - 1 - it) : it;

        // consume prefetched xW/mask into acc
        f32x4 acc[8][2];
        #pragma unroll
        for (int tau = 0; tau < 8; ++tau)
            #pragma unroll
            for (int Mt = 0; Mt < 2; ++Mt)
                #pragma unroll
                for (int r = 0; r < 4; ++r)
                    acc[tau][Mt][r] = fmaf(mkn[Mt][r], xwn[tau][Mt][r], bias[tau]);

        // prefetch next step's xW/mask (overlaps K-loop + epilogue + barrier)
        {
            const int tn = (it + 1 < nsteps) ? (dir ? t - 1 : t + 1) : t;
            const f32x4* xb4 = (const f32x4*)xWP
                + ((size_t)(tn * 4 + bh * 2) * 4096 + w * 512 + lane);
            #pragma unroll
            for (int tau = 0; tau < 8; ++tau)
                #pragma unroll
                for (int Mt = 0; Mt < 2; ++Mt)
                    xwn[tau][Mt] = xb4[Mt * 4096 + tau * 64];
            #pragma unroll
            for (int Mt = 0; Mt < 2; ++Mt)
                mkn[Mt] = ((const f32x4*)mask_t)[(n_seq * 32 + tn) * 16
                                                 + bh * 8 + Mt * 4 + quad];
        }

        // K loop: h from LDS, W streamed (each fragment feeds 2 MFMAs)
        if (it > 0) {
            #pragma unroll
            for (int kt = 0; kt < 8; ++kt) {
                const bf16x8 a0 = *(const bf16x8*)&h_lds[cur][l15][kt * 32 + quad * 8];
                const bf16x8 a1 = *(const bf16x8*)&h_lds[cur][l15 + 16][kt * 32 + quad * 8];
                #pragma unroll
                for (int tau = 0; tau < 8; ++tau) {
                    const bf16x8 bfr = *(const bf16x8*)(wbase + (kt * 8 + tau) * 512);
                    acc[tau][0] = __builtin_amdgcn_mfma_f32_16x16x32_bf16(
                        a0, bfr, acc[tau][0], 0, 0, 0);
                    acc[tau][1] = __builtin_amdgcn_mfma_f32_16x16x32_bf16(
                        a1, bfr, acc[tau][1], 0, 0, 0);
                }
            }
        }

        // epilogue: lane owns units u = w*32+q*16+l15, rows m = Mt*16+quad*4+r
        const int nxt = cur ^ 1;
        #pragma unroll
        for (int q = 0; q < 2; ++q)
            #pragma unroll
            for (int Mt = 0; Mt < 2; ++Mt)
                #pragma unroll
                for (int r = 0; r < 4; ++r) {
                    const int ci = (q * 2 + Mt) * 4 + r;
                    const float gI = acc[0 + q][Mt][r];
                    const float gF = acc[2 + q][Mt][r];
                    const float gG = acc[4 + q][Mt][r];
                    const float gO = acc[6 + q][Mt][r];
                    const float ct = sigm(gF) * c[ci] + sigm(gI) * tanh_f(gG);
                    c[ci] = ct;
                    const float hn = sigm(gO) * tanh_f(ct);
                    const int m = Mt * 16 + quad * 4 + r;
                    const int u = w * 32 + q * 16 + l15;
                    h_lds[nxt][m][u] = f2bf(hn);
                    if (it == nsteps - 1)
                        y[((size_t)(bh * 32 + m) * kN + n_seq) * (2 * kH)
                          + dir * kH + u] = hn;
                }
        if (it + 1 < nsteps) __syncthreads();
        cur = nxt;
    }
}

// ---------------------------------------------------------------------------
// k3: out = relu(y @ W_fc.T + b_fc). 64 blocks x 32 rows; 256 thr;
// 4x4 register tile; W_fc streamed once per 32 rows (16 MB total).
// ---------------------------------------------------------------------------
__global__ __launch_bounds__(256) void k3_out(
    const float* __restrict__ y, const float* __restrict__ WfcT,
    const float* __restrict__ b_fc, float* __restrict__ out)
{
    __shared__ float ys[32][512];               // 64 KB
    const int tid = threadIdx.x;
    const int r0  = blockIdx.x * 32;
    for (int i = tid; i < 4096; i += 256)
        ((f32x4*)ys)[i] = ((const f32x4*)(y + (size_t)r0 * 512))[i];
    __syncthreads();

    const int rowg = tid >> 5;                  // 0..7 -> rows rowg*4..+3
    const int cg   = tid & 31;                  // cols cg*4..+3

    f32x4 acc[4];
    #pragma unroll
    for (int r = 0; r < 4; ++r) acc[r] = (f32x4){0.f, 0.f, 0.f, 0.f};

    #pragma unroll 4
    for (int k = 0; k < 512; ++k) {
        const f32x4 wv = *(const f32x4*)&WfcT[(size_t)k * 128 + cg * 4];
        #pragma unroll
        for (int r = 0; r < 4; ++r) {
            const float yv = ys[rowg * 4 + r][k];
            #pragma unroll
            for (int j = 0; j < 4; ++j)
                acc[r][j] = fmaf(yv, wv[j], acc[r][j]);
        }
    }

    const f32x4 bv = *(const f32x4*)&b_fc[cg * 4];
    #pragma unroll
    for (int r = 0; r < 4; ++r) {
        f32x4 o;
        #pragma unroll
        for (int j = 0; j < 4; ++j) o[j] = fmaxf(acc[r][j] + bv[j], 0.f);
        *(f32x4*)&out[(size_t)(r0 + rowg * 4 + r) * 128 + cg * 4] = o;
    }
}

// ---------------------------------------------------------------------------
extern "C" void kernel_launch(void* const* d_in, const int* in_sizes, int n_in,
                              void* d_out, int out_size, void* d_ws, size_t ws_size,
                              hipStream_t stream) {
    const float* x      = (const float*)d_in[0];
    const float* mask   = (const float*)d_in[1];
    const float* W_ih_f = (const float*)d_in[2];
    const float* W_hh_f = (const float*)d_in[3];
    const float* b_f    = (const float*)d_in[4];
    const float* W_ih_r = (const float*)d_in[5];
    const float* W_hh_r = (const float*)d_in[6];
    const float* b_r    = (const float*)d_in[7];
    const float* W_fc   = (const float*)d_in[8];
    const float* b_fc   = (const float*)d_in[9];
    float* out = (float*)d_out;

    float* ws     = (float*)d_ws;
    float* WihT_f = ws;                        // 131072 f
    float* WihT_r = WihT_f + 131072;           // 131072 f
    float* WfcT   = WihT_r + 131072;           // 65536 f
    float* mask_t = WfcT + 65536;              // 65536 f
    float* xWP_f  = mask_t + 65536;            // 2097152 f
    float* xWP_r  = xWP_f + 2097152;           // 2097152 f
    float* yb     = xWP_r + 2097152;           // 1048576 f
    short* Wp_f   = (short*)(yb + 1048576);    // 262144 bf16
    short* Wp_r   = Wp_f + 262144;             // 262144 bf16

    prep_k<<<456, dim3(32, 8), 0, stream>>>(
        W_ih_f, W_ih_r, W_hh_f, W_hh_r, W_fc, mask,
        WihT_f, WihT_r, WfcT, mask_t, Wp_f, Wp_r);

    k1_xw<<<128, 512, 0, stream>>>(x, WihT_f, WihT_r, xWP_f, xWP_r);
    k2_lstm<<<128, 512, 0, stream>>>(mask_t, xWP_f, xWP_r, Wp_f, Wp_r, b_f, b_r, yb);
    k3_out<<<64, 256, 0, stream>>>(yb, WfcT, b_fc, out);
}

// Round 4
// 444.025 us; speedup vs baseline: 1.4212x; 1.4212x over previous
//
#include <hip/hip_runtime.h>
#include <math.h>

// Problem constants
constexpr int kB    = 64;
constexpr int kN    = 32;
constexpr int kDIN  = 128;
constexpr int kH    = 256;
constexpr int kG4   = 1024;   // 4*H
constexpr int kDOUT = 128;
constexpr int kBN   = 2048;   // B*N

typedef __attribute__((ext_vector_type(8))) short bf16x8;
typedef __attribute__((ext_vector_type(4))) float f32x4;

// fast sigmoid/tanh: v_exp_f32 + v_rcp_f32 (1-2 ulp, far below bf16-h noise)
__device__ __forceinline__ float sigm(float x) {
    return __builtin_amdgcn_rcpf(1.0f + __expf(-x));
}
__device__ __forceinline__ float tanh_f(float x) {
    return 1.0f - 2.0f * __builtin_amdgcn_rcpf(1.0f + __expf(2.0f * x));
}

// fp32 -> bf16 bits, round-to-nearest-even
__device__ __forceinline__ short f2bf(float f) {
    union { float f; unsigned u; } v; v.f = f;
    unsigned r = v.u + 0x7fffu + ((v.u >> 16) & 1u);
    return (short)(r >> 16);
}

// ---------------------------------------------------------------------------
// prep:
//   [0,128)   transpose W_ih_f (1024x128) -> WihT_f [k][gate]
//   [128,256) transpose W_ih_r            -> WihT_r
//   [256,320) transpose W_fc   (128x512)  -> WfcT   [k][dout]
//   [320,448) pack W_hh (bf16) into per-wave MFMA fragment order:
//             Wp[((wv*8+kt)*8+tau)*512 + lane*8 + j]
//               = W_hh[(tau>>1)*256 + wv*32 + (tau&1)*16 + l15][kt*32+quad*8+j]
//   [448,456) transpose mask -> mask_t [n][t][b]
// ---------------------------------------------------------------------------
__global__ __launch_bounds__(256) void prep_k(
    const float* __restrict__ Wihf, const float* __restrict__ Wihr,
    const float* __restrict__ Whhf, const float* __restrict__ Whhr,
    const float* __restrict__ Wfc,  const float* __restrict__ mask,
    float* __restrict__ WihTf, float* __restrict__ WihTr,
    float* __restrict__ WfcT,  float* __restrict__ mask_t,
    short* __restrict__ Wp_f,  short* __restrict__ Wp_r)
{
    const int bx  = blockIdx.x;
    const int tid = threadIdx.y * 32 + threadIdx.x;

    if (bx >= 448) {                       // mask transpose: [b][n][t] -> [n][t][b]
        const int base = (bx - 448) * 8192 + tid;
        #pragma unroll
        for (int i = 0; i < 32; ++i) {
            const int idx = base + i * 256;
            const int n = idx >> 11, tt = (idx >> 6) & 31, b = idx & 63;
            mask_t[idx] = mask[(size_t)b * 1024 + n * 32 + tt];
        }
        return;
    }
    if (bx >= 320) {                       // W_hh fragment pack
        const int idx = bx - 320;
        const int dir = idx >> 6;
        const int wv  = (idx >> 3) & 7;
        const int kt  = idx & 7;
        const float* src = dir ? Whhr : Whhf;
        short* dst = (dir ? Wp_r : Wp_f) + (size_t)((wv * 8 + kt) * 8) * 512;
        for (int i = tid; i < 512; i += 256) {
            const int tau = i >> 6, lane = i & 63;
            const int qd = lane >> 4, l = lane & 15;
            const int gate = (tau >> 1) * 256 + wv * 32 + (tau & 1) * 16 + l;
            const int ks = kt * 32 + qd * 8;
            bf16x8 v;
            #pragma unroll
            for (int j = 0; j < 8; ++j) v[j] = f2bf(src[(size_t)gate * kH + ks + j]);
            *(bf16x8*)(dst + tau * 512 + lane * 8) = v;
        }
        return;
    }
    __shared__ float tile[32][33];
    const float* src; float* dst; int R, C, t;
    if (bx < 128)      { src = Wihf; dst = WihTf; R = 1024; C = 128; t = bx; }
    else if (bx < 256) { src = Wihr; dst = WihTr; R = 1024; C = 128; t = bx - 128; }
    else               { src = Wfc;  dst = WfcT;  R = 128;  C = 512; t = bx - 256; }
    const int tilesX = C / 32;
    const int c0 = (t % tilesX) * 32;
    const int r0 = (t / tilesX) * 32;
    const int tx = threadIdx.x, ty = threadIdx.y;
    #pragma unroll
    for (int i = ty; i < 32; i += 8)
        tile[i][tx] = src[(size_t)(r0 + i) * C + (c0 + tx)];
    __syncthreads();
    #pragma unroll
    for (int i = ty; i < 32; i += 8)
        dst[(size_t)(c0 + i) * R + (r0 + tx)] = tile[tx][i];
}

// ---------------------------------------------------------------------------
// k1: xW = x @ W_ih.T, written in k2's packed-fragment layout (M=16 tiles):
//   xWP[(t*4+bq4)*4096 + wg*512 + taug*64 + qd*16 + l15]  (f32x4 over r)
// Grid 128 = dir(2) x t(32) x bq(2: 32 rows). 512 thr; 8-row x 8-gate reg tile.
// ---------------------------------------------------------------------------
__global__ __launch_bounds__(512) void k1_xw(
    const float* __restrict__ x,
    const float* __restrict__ WihT_f, const float* __restrict__ WihT_r,
    float* __restrict__ xWP_f, float* __restrict__ xWP_r)
{
    __shared__ float xs[32][128];               // 16 KB
    const int tid  = threadIdx.x;
    const int bx   = blockIdx.x;
    const int dir  = bx >> 6;
    const int rest = bx & 63;
    const int t    = rest >> 1;
    const int bq   = rest & 1;                  // 32-batch half
    const float* __restrict__ WT = dir ? WihT_r : WihT_f;
    float* __restrict__ xWP = dir ? xWP_r : xWP_f;

    for (int i = tid; i < 1024; i += 512) {
        const int rr = i >> 5, c4 = i & 31;
        *(f32x4*)&xs[rr][c4 * 4] =
            *(const f32x4*)&x[((size_t)(bq * 32 + rr) * 32 + t) * 128 + c4 * 4];
    }
    __syncthreads();

    const int rowg = tid >> 7;    // 0..3 -> rows rowg*8..+7
    const int gg   = tid & 127;   // gates {gg*4+j} and {512+gg*4+j}

    float acc0[8][4], acc1[8][4];
    #pragma unroll
    for (int r = 0; r < 8; ++r)
        #pragma unroll
        for (int j = 0; j < 4; ++j) { acc0[r][j] = 0.f; acc1[r][j] = 0.f; }

    for (int k4 = 0; k4 < 32; ++k4) {
        f32x4 w0[4], w1[4], xv[8];
        #pragma unroll
        for (int kk = 0; kk < 4; ++kk) {
            w0[kk] = *(const f32x4*)&WT[(size_t)(k4 * 4 + kk) * 1024 + gg * 4];
            w1[kk] = *(const f32x4*)&WT[(size_t)(k4 * 4 + kk) * 1024 + 512 + gg * 4];
        }
        #pragma unroll
        for (int r = 0; r < 8; ++r) xv[r] = *(const f32x4*)&xs[rowg * 8 + r][k4 * 4];
        #pragma unroll
        for (int r = 0; r < 8; ++r)
            #pragma unroll
            for (int kk = 0; kk < 4; ++kk) {
                const float xk = xv[r][kk];
                #pragma unroll
                for (int j = 0; j < 4; ++j) {
                    acc0[r][j] = fmaf(xk, w0[kk][j], acc0[r][j]);
                    acc1[r][j] = fmaf(xk, w1[kk][j], acc1[r][j]);
                }
            }
    }

    #pragma unroll
    for (int hf = 0; hf < 2; ++hf)
        #pragma unroll
        for (int j = 0; j < 4; ++j) {
            const int g    = hf * 512 + gg * 4 + j;
            const int l15g = g & 15;
            const int qg   = (g >> 4) & 1;
            const int wg   = (g >> 5) & 7;
            const int taug = (g >> 8) * 2 + qg;
            #pragma unroll
            for (int p = 0; p < 2; ++p) {
                const int b   = bq * 32 + rowg * 8 + p * 4;   // +r in vector
                const int bq4 = b >> 4;
                const int qd  = (b >> 2) & 3;
                f32x4 v;
                #pragma unroll
                for (int r = 0; r < 4; ++r)
                    v[r] = hf ? acc1[p * 4 + r][j] : acc0[p * 4 + r][j];
                ((f32x4*)xWP)[(size_t)(t * 4 + bq4) * 4096 + wg * 512 + taug * 64
                              + qd * 16 + l15g] = v;
            }
        }
}

// ---------------------------------------------------------------------------
// k2: bidirectional LSTM recurrence, bf16 MFMA fp32 accumulate.
// Grid 256 = dir(2) x n(32) x bq(4: 16 batches). 1024 thr = 16 waves, M=16.
// KEY CHANGE (r4): the ENTIRE per-wave W_hh slice lives in VGPRs.
//   Wave w owns units w*16+l15, ALL 4 gates: 8kt x 4g fragments = 128 VGPRs.
//   K-loop = 8 ds_read_b128 + 32 MFMA, ZERO global loads -> kills the
//   512 KB/block-step L2 W stream that bounded rounds 0-3 (~9k cy/step).
// One-step-deep register prefetch of packed xW+mask retained.
// ---------------------------------------------------------------------------
__global__ __launch_bounds__(1024) void k2_lstm(
    const float* __restrict__ mask_t,
    const float* __restrict__ xWP_f, const float* __restrict__ xWP_r,
    const short* __restrict__ Wp_f, const short* __restrict__ Wp_r,
    const float* __restrict__ b_f,  const float* __restrict__ b_r,
    float* __restrict__ y)
{
    constexpr int HP = 272;
    __shared__ short h_lds[2][16][HP];          // 17.4 KB

    const int tid  = threadIdx.x;
    const int w    = tid >> 6;                  // 0..15
    const int lane = tid & 63;
    const int quad = lane >> 4;
    const int l15  = lane & 15;

    const int bx    = blockIdx.x;
    const int dir   = bx >> 7;                  // 0 fwd, 1 rev
    const int rest  = bx & 127;
    const int n_seq = rest >> 2;                // 0..31
    const int bq    = rest & 3;                 // batch quarter (16 each)

    const float* __restrict__ xWP = dir ? xWP_r : xWP_f;
    const short* __restrict__ Wp  = dir ? Wp_r  : Wp_f;
    const float* __restrict__ bb  = dir ? b_r   : b_f;

    // wave w <-> packed layout: wv = w>>1, tau = g*2 + (w&1)
    const int wv = w >> 1;
    const int wo = w & 1;

    float bias[4];
    #pragma unroll
    for (int g = 0; g < 4; ++g)
        bias[g] = bb[g * 256 + w * 16 + l15];

    // persist the full W slice: 8 kt x 4 gates x 16B/lane = 128 VGPRs
    bf16x8 wreg[8][4];
    #pragma unroll
    for (int kt = 0; kt < 8; ++kt)
        #pragma unroll
        for (int g = 0; g < 4; ++g)
            wreg[kt][g] = *(const bf16x8*)(
                Wp + (size_t)(((wv * 8 + kt) * 8) + g * 2 + wo) * 512 + lane * 8);

    float c[4];
    #pragma unroll
    for (int i = 0; i < 4; ++i) c[i] = 0.f;

    const int nsteps = dir ? (kN - n_seq) : (n_seq + 1);
    const int t0     = dir ? (kN - 1) : 0;

    // per-wave xW base: (t*4+bq)*4096 + (w>>1)*512 + (w&1)*64 + lane; +g*128
    const f32x4* xWPv = (const f32x4*)xWP + (wv * 512 + wo * 64 + lane);

    // initial prefetch of packed xW + mask for t0
    f32x4 xwn[4];
    f32x4 mkn;
    {
        const f32x4* xb4 = xWPv + (size_t)(t0 * 4 + bq) * 4096;
        #pragma unroll
        for (int g = 0; g < 4; ++g) xwn[g] = xb4[g * 128];
        mkn = ((const f32x4*)mask_t)[(n_seq * 32 + t0) * 16 + bq * 4 + quad];
    }

    int cur = 0;
    for (int it = 0; it < nsteps; ++it) {
        const int t = dir ? (kN - 1 - it) : it;

        // consume prefetched xW/mask into acc
        f32x4 acc[4];
        #pragma unroll
        for (int g = 0; g < 4; ++g)
            #pragma unroll
            for (int r = 0; r < 4; ++r)
                acc[g][r] = fmaf(mkn[r], xwn[g][r], bias[g]);

        // prefetch next step's xW/mask (overlaps K-loop + epilogue + barrier)
        {
            const int tn = (it + 1 < nsteps) ? (dir ? t - 1 : t + 1) : t;
            const f32x4* xb4 = xWPv + (size_t)(tn * 4 + bq) * 4096;
            #pragma unroll
            for (int g = 0; g < 4; ++g) xwn[g] = xb4[g * 128];
            mkn = ((const f32x4*)mask_t)[(n_seq * 32 + tn) * 16 + bq * 4 + quad];
        }

        // K loop: h from LDS, W from registers -- no global traffic
        if (it > 0) {
            #pragma unroll
            for (int kt = 0; kt < 8; ++kt) {
                const bf16x8 a = *(const bf16x8*)&h_lds[cur][l15][kt * 32 + quad * 8];
                #pragma unroll
                for (int g = 0; g < 4; ++g)
                    acc[g] = __builtin_amdgcn_mfma_f32_16x16x32_bf16(
                        a, wreg[kt][g], acc[g], 0, 0, 0);
            }
        }

        // epilogue: lane owns unit u = w*16+l15, rows m = quad*4+r
        const int nxt = cur ^ 1;
        const int u = w * 16 + l15;
        #pragma unroll
        for (int r = 0; r < 4; ++r) {
            const float gI = acc[0][r];
            const float gF = acc[1][r];
            const float gG = acc[2][r];
            const float gO = acc[3][r];
            const float ct = sigm(gF) * c[r] + sigm(gI) * tanh_f(gG);
            c[r] = ct;
            const float hn = sigm(gO) * tanh_f(ct);
            const int m = quad * 4 + r;
            h_lds[nxt][m][u] = f2bf(hn);
            if (it == nsteps - 1)
                y[((size_t)(bq * 16 + m) * kN + n_seq) * (2 * kH)
                  + dir * kH + u] = hn;
        }
        if (it + 1 < nsteps) __syncthreads();
        cur = nxt;
    }
}

// ---------------------------------------------------------------------------
// k3: out = relu(y @ W_fc.T + b_fc). 64 blocks x 32 rows; 256 thr;
// 4x4 register tile; W_fc streamed once per 32 rows (16 MB total).
// ---------------------------------------------------------------------------
__global__ __launch_bounds__(256) void k3_out(
    const float* __restrict__ y, const float* __restrict__ WfcT,
    const float* __restrict__ b_fc, float* __restrict__ out)
{
    __shared__ float ys[32][512];               // 64 KB
    const int tid = threadIdx.x;
    const int r0  = blockIdx.x * 32;
    for (int i = tid; i < 4096; i += 256)
        ((f32x4*)ys)[i] = ((const f32x4*)(y + (size_t)r0 * 512))[i];
    __syncthreads();

    const int rowg = tid >> 5;                  // 0..7 -> rows rowg*4..+3
    const int cg   = tid & 31;                  // cols cg*4..+3

    f32x4 acc[4];
    #pragma unroll
    for (int r = 0; r < 4; ++r) acc[r] = (f32x4){0.f, 0.f, 0.f, 0.f};

    #pragma unroll 4
    for (int k = 0; k < 512; ++k) {
        const f32x4 wv = *(const f32x4*)&WfcT[(size_t)k * 128 + cg * 4];
        #pragma unroll
        for (int r = 0; r < 4; ++r) {
            const float yv = ys[rowg * 4 + r][k];
            #pragma unroll
            for (int j = 0; j < 4; ++j)
                acc[r][j] = fmaf(yv, wv[j], acc[r][j]);
        }
    }

    const f32x4 bv = *(const f32x4*)&b_fc[cg * 4];
    #pragma unroll
    for (int r = 0; r < 4; ++r) {
        f32x4 o;
        #pragma unroll
        for (int j = 0; j < 4; ++j) o[j] = fmaxf(acc[r][j] + bv[j], 0.f);
        *(f32x4*)&out[(size_t)(r0 + rowg * 4 + r) * 128 + cg * 4] = o;
    }
}

// ---------------------------------------------------------------------------
extern "C" void kernel_launch(void* const* d_in, const int* in_sizes, int n_in,
                              void* d_out, int out_size, void* d_ws, size_t ws_size,
                              hipStream_t stream) {
    const float* x      = (const float*)d_in[0];
    const float* mask   = (const float*)d_in[1];
    const float* W_ih_f = (const float*)d_in[2];
    const float* W_hh_f = (const float*)d_in[3];
    const float* b_f    = (const float*)d_in[4];
    const float* W_ih_r = (const float*)d_in[5];
    const float* W_hh_r = (const float*)d_in[6];
    const float* b_r    = (const float*)d_in[7];
    const float* W_fc   = (const float*)d_in[8];
    const float* b_fc   = (const float*)d_in[9];
    float* out = (float*)d_out;

    float* ws     = (float*)d_ws;
    float* WihT_f = ws;                        // 131072 f
    float* WihT_r = WihT_f + 131072;           // 131072 f
    float* WfcT   = WihT_r + 131072;           // 65536 f
    float* mask_t = WfcT + 65536;              // 65536 f
    float* xWP_f  = mask_t + 65536;            // 2097152 f
    float* xWP_r  = xWP_f + 2097152;           // 2097152 f
    float* yb     = xWP_r + 2097152;           // 1048576 f
    short* Wp_f   = (short*)(yb + 1048576);    // 262144 bf16
    short* Wp_r   = Wp_f + 262144;             // 262144 bf16

    prep_k<<<456, dim3(32, 8), 0, stream>>>(
        W_ih_f, W_ih_r, W_hh_f, W_hh_r, W_fc, mask,
        WihT_f, WihT_r, WfcT, mask_t, Wp_f, Wp_r);

    k1_xw<<<128, 512, 0, stream>>>(x, WihT_f, WihT_r, xWP_f, xWP_r);
    k2_lstm<<<256, 1024, 0, stream>>>(mask_t, xWP_f, xWP_r, Wp_f, Wp_r, b_f, b_r, yb);
    k3_out<<<64, 256, 0, stream>>>(yb, WfcT, b_fc, out);
}

// Round 5
// 304.865 us; speedup vs baseline: 2.0699x; 1.4565x over previous
//
#include <hip/hip_runtime.h>
#include <math.h>

// Problem constants
constexpr int kB    = 64;
constexpr int kN    = 32;
constexpr int kDIN  = 128;
constexpr int kH    = 256;
constexpr int kG4   = 1024;   // 4*H
constexpr int kDOUT = 128;
constexpr int kBN   = 2048;   // B*N

typedef __attribute__((ext_vector_type(8))) short bf16x8;
typedef __attribute__((ext_vector_type(4))) float f32x4;

// fast sigmoid/tanh: v_exp_f32 + v_rcp_f32 (1-2 ulp, far below bf16-h noise)
__device__ __forceinline__ float sigm(float x) {
    return __builtin_amdgcn_rcpf(1.0f + __expf(-x));
}
__device__ __forceinline__ float tanh_f(float x) {
    return 1.0f - 2.0f * __builtin_amdgcn_rcpf(1.0f + __expf(2.0f * x));
}

// fp32 -> bf16 bits, round-to-nearest-even
__device__ __forceinline__ short f2bf(float f) {
    union { float f; unsigned u; } v; v.f = f;
    unsigned r = v.u + 0x7fffu + ((v.u >> 16) & 1u);
    return (short)(r >> 16);
}

// ---------------------------------------------------------------------------
// prep:
//   [0,128)   transpose W_ih_f (1024x128) -> WihT_f [k][gate]
//   [128,256) transpose W_ih_r            -> WihT_r
//   [256,320) transpose W_fc   (128x512)  -> WfcT   [k][dout]
//   [320,448) pack W_hh (bf16) into per-wave MFMA fragment order:
//             Wp[((wv*8+kt)*8+tau)*512 + lane*8 + j]
//               = W_hh[(tau>>1)*256 + wv*32 + (tau&1)*16 + l15][kt*32+quad*8+j]
//   [448,456) transpose mask -> mask_t [n][t][b]
// ---------------------------------------------------------------------------
__global__ __launch_bounds__(256) void prep_k(
    const float* __restrict__ Wihf, const float* __restrict__ Wihr,
    const float* __restrict__ Whhf, const float* __restrict__ Whhr,
    const float* __restrict__ Wfc,  const float* __restrict__ mask,
    float* __restrict__ WihTf, float* __restrict__ WihTr,
    float* __restrict__ WfcT,  float* __restrict__ mask_t,
    short* __restrict__ Wp_f,  short* __restrict__ Wp_r)
{
    const int bx  = blockIdx.x;
    const int tid = threadIdx.y * 32 + threadIdx.x;

    if (bx >= 448) {                       // mask transpose: [b][n][t] -> [n][t][b]
        const int base = (bx - 448) * 8192 + tid;
        #pragma unroll
        for (int i = 0; i < 32; ++i) {
            const int idx = base + i * 256;
            const int n = idx >> 11, tt = (idx >> 6) & 31, b = idx & 63;
            mask_t[idx] = mask[(size_t)b * 1024 + n * 32 + tt];
        }
        return;
    }
    if (bx >= 320) {                       // W_hh fragment pack
        const int idx = bx - 320;
        const int dir = idx >> 6;
        const int wv  = (idx >> 3) & 7;
        const int kt  = idx & 7;
        const float* src = dir ? Whhr : Whhf;
        short* dst = (dir ? Wp_r : Wp_f) + (size_t)((wv * 8 + kt) * 8) * 512;
        for (int i = tid; i < 512; i += 256) {
            const int tau = i >> 6, lane = i & 63;
            const int qd = lane >> 4, l = lane & 15;
            const int gate = (tau >> 1) * 256 + wv * 32 + (tau & 1) * 16 + l;
            const int ks = kt * 32 + qd * 8;
            bf16x8 v;
            #pragma unroll
            for (int j = 0; j < 8; ++j) v[j] = f2bf(src[(size_t)gate * kH + ks + j]);
            *(bf16x8*)(dst + tau * 512 + lane * 8) = v;
        }
        return;
    }
    __shared__ float tile[32][33];
    const float* src; float* dst; int R, C, t;
    if (bx < 128)      { src = Wihf; dst = WihTf; R = 1024; C = 128; t = bx; }
    else if (bx < 256) { src = Wihr; dst = WihTr; R = 1024; C = 128; t = bx - 128; }
    else               { src = Wfc;  dst = WfcT;  R = 128;  C = 512; t = bx - 256; }
    const int tilesX = C / 32;
    const int c0 = (t % tilesX) * 32;
    const int r0 = (t / tilesX) * 32;
    const int tx = threadIdx.x, ty = threadIdx.y;
    #pragma unroll
    for (int i = ty; i < 32; i += 8)
        tile[i][tx] = src[(size_t)(r0 + i) * C + (c0 + tx)];
    __syncthreads();
    #pragma unroll
    for (int i = ty; i < 32; i += 8)
        dst[(size_t)(c0 + i) * R + (r0 + tx)] = tile[tx][i];
}

// ---------------------------------------------------------------------------
// k1: xW = x @ W_ih.T, written in k2's packed-fragment layout (M=16 tiles):
//   xWP[(t*4+bq4)*4096 + wg*512 + taug*64 + qd*16 + l15]  (f32x4 over r)
// Grid 128 = dir(2) x t(32) x bq(2: 32 rows). 512 thr; 8-row x 8-gate reg tile.
// ---------------------------------------------------------------------------
__global__ __launch_bounds__(512) void k1_xw(
    const float* __restrict__ x,
    const float* __restrict__ WihT_f, const float* __restrict__ WihT_r,
    float* __restrict__ xWP_f, float* __restrict__ xWP_r)
{
    __shared__ float xs[32][128];               // 16 KB
    const int tid  = threadIdx.x;
    const int bx   = blockIdx.x;
    const int dir  = bx >> 6;
    const int rest = bx & 63;
    const int t    = rest >> 1;
    const int bq   = rest & 1;                  // 32-batch half
    const float* __restrict__ WT = dir ? WihT_r : WihT_f;
    float* __restrict__ xWP = dir ? xWP_r : xWP_f;

    for (int i = tid; i < 1024; i += 512) {
        const int rr = i >> 5, c4 = i & 31;
        *(f32x4*)&xs[rr][c4 * 4] =
            *(const f32x4*)&x[((size_t)(bq * 32 + rr) * 32 + t) * 128 + c4 * 4];
    }
    __syncthreads();

    const int rowg = tid >> 7;    // 0..3 -> rows rowg*8..+7
    const int gg   = tid & 127;   // gates {gg*4+j} and {512+gg*4+j}

    float acc0[8][4], acc1[8][4];
    #pragma unroll
    for (int r = 0; r < 8; ++r)
        #pragma unroll
        for (int j = 0; j < 4; ++j) { acc0[r][j] = 0.f; acc1[r][j] = 0.f; }

    for (int k4 = 0; k4 < 32; ++k4) {
        f32x4 w0[4], w1[4], xv[8];
        #pragma unroll
        for (int kk = 0; kk < 4; ++kk) {
            w0[kk] = *(const f32x4*)&WT[(size_t)(k4 * 4 + kk) * 1024 + gg * 4];
            w1[kk] = *(const f32x4*)&WT[(size_t)(k4 * 4 + kk) * 1024 + 512 + gg * 4];
        }
        #pragma unroll
        for (int r = 0; r < 8; ++r) xv[r] = *(const f32x4*)&xs[rowg * 8 + r][k4 * 4];
        #pragma unroll
        for (int r = 0; r < 8; ++r)
            #pragma unroll
            for (int kk = 0; kk < 4; ++kk) {
                const float xk = xv[r][kk];
                #pragma unroll
                for (int j = 0; j < 4; ++j) {
                    acc0[r][j] = fmaf(xk, w0[kk][j], acc0[r][j]);
                    acc1[r][j] = fmaf(xk, w1[kk][j], acc1[r][j]);
                }
            }
    }

    #pragma unroll
    for (int hf = 0; hf < 2; ++hf)
        #pragma unroll
        for (int j = 0; j < 4; ++j) {
            const int g    = hf * 512 + gg * 4 + j;
            const int l15g = g & 15;
            const int qg   = (g >> 4) & 1;
            const int wg   = (g >> 5) & 7;
            const int taug = (g >> 8) * 2 + qg;
            #pragma unroll
            for (int p = 0; p < 2; ++p) {
                const int b   = bq * 32 + rowg * 8 + p * 4;   // +r in vector
                const int bq4 = b >> 4;
                const int qd  = (b >> 2) & 3;
                f32x4 v;
                #pragma unroll
                for (int r = 0; r < 4; ++r)
                    v[r] = hf ? acc1[p * 4 + r][j] : acc0[p * 4 + r][j];
                ((f32x4*)xWP)[(size_t)(t * 4 + bq4) * 4096 + wg * 512 + taug * 64
                              + qd * 16 + l15g] = v;
            }
        }
}

// ---------------------------------------------------------------------------
// k2: bidirectional LSTM recurrence, bf16 MFMA fp32 accumulate.
// Grid 256 = dir(2) x n(32) x bq(4: 16 batches). 1024 thr = 16 waves, M=16.
// W split three ways (W/dir = 512 KB = a full CU VGPR file; r4's full-persist
// attempt spilled everything to scratch at VGPR_Count=64):
//   kt 0..3: persisted in VGPRs (64 regs/thread; fits 128-cap w/ headroom)
//   kt 4..5: parked in LDS once (128 KB; wave-private slices, no barriers)
//   kt 6..7: streamed per step from L2-resident packed Wp (128 KB/step)
// __launch_bounds__(1024, 4): pin 4 waves/SIMD -> 128-VGPR cap, stops the
// occupancy heuristic that chose 64 VGPRs (and spilled) in round 4.
// One-step-deep register prefetch of packed xW+mask retained.
// ---------------------------------------------------------------------------
__global__ __launch_bounds__(1024, 4) void k2_lstm(
    const float* __restrict__ mask_t,
    const float* __restrict__ xWP_f, const float* __restrict__ xWP_r,
    const short* __restrict__ Wp_f, const short* __restrict__ Wp_r,
    const float* __restrict__ b_f,  const float* __restrict__ b_r,
    float* __restrict__ y)
{
    constexpr int HP = 272;
    __shared__ short h_lds[2][16][HP];          // 17408 B
    __shared__ short w_lds[16][8][512];         // 131072 B: kt=4,5 x 4g per wave

    const int tid  = threadIdx.x;
    const int w    = tid >> 6;                  // 0..15
    const int lane = tid & 63;
    const int quad = lane >> 4;
    const int l15  = lane & 15;

    const int bx    = blockIdx.x;
    const int dir   = bx >> 7;                  // 0 fwd, 1 rev
    const int rest  = bx & 127;
    const int n_seq = rest >> 2;                // 0..31
    const int bq    = rest & 3;                 // batch quarter (16 each)

    const float* __restrict__ xWP = dir ? xWP_r : xWP_f;
    const short* __restrict__ Wp  = dir ? Wp_r  : Wp_f;
    const float* __restrict__ bb  = dir ? b_r   : b_f;

    // wave w <-> packed layout: wv = w>>1, tau = g*2 + (w&1)
    const int wv = w >> 1;
    const int wo = w & 1;

    float bias[4];
    #pragma unroll
    for (int g = 0; g < 4; ++g)
        bias[g] = bb[g * 256 + w * 16 + l15];

    // tier 1: persist kt = 0..3 in registers (64 VGPRs)
    bf16x8 wreg[4][4];
    #pragma unroll
    for (int kt = 0; kt < 4; ++kt)
        #pragma unroll
        for (int g = 0; g < 4; ++g)
            wreg[kt][g] = *(const bf16x8*)(
                Wp + (size_t)((wv * 8 + kt) * 8 + g * 2 + wo) * 512 + lane * 8);

    // tier 2: park kt = 4..5 in this wave's private LDS stash.
    // Wave reads only its own slice -> ordinary lgkmcnt ordering, no barrier.
    #pragma unroll
    for (int f = 0; f < 8; ++f) {
        const int kt = 4 + (f >> 2), g = f & 3;
        *(bf16x8*)&w_lds[w][f][lane * 8] = *(const bf16x8*)(
            Wp + (size_t)((wv * 8 + kt) * 8 + g * 2 + wo) * 512 + lane * 8);
    }

    float c[4];
    #pragma unroll
    for (int i = 0; i < 4; ++i) c[i] = 0.f;

    const int nsteps = dir ? (kN - n_seq) : (n_seq + 1);
    const int t0     = dir ? (kN - 1) : 0;

    // per-wave xW base: (t*4+bq)*4096 + wv*512 + wo*64 + lane; +g*128
    const f32x4* xWPv = (const f32x4*)xWP + (wv * 512 + wo * 64 + lane);

    // initial prefetch of packed xW + mask for t0
    f32x4 xwn[4];
    f32x4 mkn;
    {
        const f32x4* xb4 = xWPv + (size_t)(t0 * 4 + bq) * 4096;
        #pragma unroll
        for (int g = 0; g < 4; ++g) xwn[g] = xb4[g * 128];
        mkn = ((const f32x4*)mask_t)[(n_seq * 32 + t0) * 16 + bq * 4 + quad];
    }

    int cur = 0;
    for (int it = 0; it < nsteps; ++it) {
        const int t = dir ? (kN - 1 - it) : it;

        // consume prefetched xW/mask into acc
        f32x4 acc[4];
        #pragma unroll
        for (int g = 0; g < 4; ++g)
            #pragma unroll
            for (int r = 0; r < 4; ++r)
                acc[g][r] = fmaf(mkn[r], xwn[g][r], bias[g]);

        // prefetch next step's xW/mask (overlaps K-loop + epilogue + barrier)
        {
            const int tn = (it + 1 < nsteps) ? (dir ? t - 1 : t + 1) : t;
            const f32x4* xb4 = xWPv + (size_t)(tn * 4 + bq) * 4096;
            #pragma unroll
            for (int g = 0; g < 4; ++g) xwn[g] = xb4[g * 128];
            mkn = ((const f32x4*)mask_t)[(n_seq * 32 + tn) * 16 + bq * 4 + quad];
        }

        // K loop: kt 0..3 regs, kt 4..5 LDS stash, kt 6..7 streamed from L2
        if (it > 0) {
            #pragma unroll
            for (int kt = 0; kt < 4; ++kt) {
                const bf16x8 a = *(const bf16x8*)&h_lds[cur][l15][kt * 32 + quad * 8];
                #pragma unroll
                for (int g = 0; g < 4; ++g)
                    acc[g] = __builtin_amdgcn_mfma_f32_16x16x32_bf16(
                        a, wreg[kt][g], acc[g], 0, 0, 0);
            }
            #pragma unroll
            for (int kk = 0; kk < 2; ++kk) {
                const int kt = 4 + kk;
                const bf16x8 a = *(const bf16x8*)&h_lds[cur][l15][kt * 32 + quad * 8];
                #pragma unroll
                for (int g = 0; g < 4; ++g) {
                    const bf16x8 wf = *(const bf16x8*)&w_lds[w][kk * 4 + g][lane * 8];
                    acc[g] = __builtin_amdgcn_mfma_f32_16x16x32_bf16(
                        a, wf, acc[g], 0, 0, 0);
                }
            }
            #pragma unroll
            for (int kk = 0; kk < 2; ++kk) {
                const int kt = 6 + kk;
                const bf16x8 a = *(const bf16x8*)&h_lds[cur][l15][kt * 32 + quad * 8];
                #pragma unroll
                for (int g = 0; g < 4; ++g) {
                    const bf16x8 wf = *(const bf16x8*)(
                        Wp + (size_t)((wv * 8 + kt) * 8 + g * 2 + wo) * 512 + lane * 8);
                    acc[g] = __builtin_amdgcn_mfma_f32_16x16x32_bf16(
                        a, wf, acc[g], 0, 0, 0);
                }
            }
        }

        // epilogue: lane owns unit u = w*16+l15, rows m = quad*4+r
        const int nxt = cur ^ 1;
        const int u = w * 16 + l15;
        #pragma unroll
        for (int r = 0; r < 4; ++r) {
            const float gI = acc[0][r];
            const float gF = acc[1][r];
            const float gG = acc[2][r];
            const float gO = acc[3][r];
            const float ct = sigm(gF) * c[r] + sigm(gI) * tanh_f(gG);
            c[r] = ct;
            const float hn = sigm(gO) * tanh_f(ct);
            const int m = quad * 4 + r;
            h_lds[nxt][m][u] = f2bf(hn);
            if (it == nsteps - 1)
                y[((size_t)(bq * 16 + m) * kN + n_seq) * (2 * kH)
                  + dir * kH + u] = hn;
        }
        if (it + 1 < nsteps) __syncthreads();
        cur = nxt;
    }
}

// ---------------------------------------------------------------------------
// k3: out = relu(y @ W_fc.T + b_fc). 64 blocks x 32 rows; 256 thr;
// 4x4 register tile; W_fc streamed once per 32 rows (16 MB total).
// ---------------------------------------------------------------------------
__global__ __launch_bounds__(256) void k3_out(
    const float* __restrict__ y, const float* __restrict__ WfcT,
    const float* __restrict__ b_fc, float* __restrict__ out)
{
    __shared__ float ys[32][512];               // 64 KB
    const int tid = threadIdx.x;
    const int r0  = blockIdx.x * 32;
    for (int i = tid; i < 4096; i += 256)
        ((f32x4*)ys)[i] = ((const f32x4*)(y + (size_t)r0 * 512))[i];
    __syncthreads();

    const int rowg = tid >> 5;                  // 0..7 -> rows rowg*4..+3
    const int cg   = tid & 31;                  // cols cg*4..+3

    f32x4 acc[4];
    #pragma unroll
    for (int r = 0; r < 4; ++r) acc[r] = (f32x4){0.f, 0.f, 0.f, 0.f};

    #pragma unroll 4
    for (int k = 0; k < 512; ++k) {
        const f32x4 wv = *(const f32x4*)&WfcT[(size_t)k * 128 + cg * 4];
        #pragma unroll
        for (int r = 0; r < 4; ++r) {
            const float yv = ys[rowg * 4 + r][k];
            #pragma unroll
            for (int j = 0; j < 4; ++j)
                acc[r][j] = fmaf(yv, wv[j], acc[r][j]);
        }
    }

    const f32x4 bv = *(const f32x4*)&b_fc[cg * 4];
    #pragma unroll
    for (int r = 0; r < 4; ++r) {
        f32x4 o;
        #pragma unroll
        for (int j = 0; j < 4; ++j) o[j] = fmaxf(acc[r][j] + bv[j], 0.f);
        *(f32x4*)&out[(size_t)(r0 + rowg * 4 + r) * 128 + cg * 4] = o;
    }
}

// ---------------------------------------------------------------------------
extern "C" void kernel_launch(void* const* d_in, const int* in_sizes, int n_in,
                              void* d_out, int out_size, void* d_ws, size_t ws_size,
                              hipStream_t stream) {
    const float* x      = (const float*)d_in[0];
    const float* mask   = (const float*)d_in[1];
    const float* W_ih_f = (const float*)d_in[2];
    const float* W_hh_f = (const float*)d_in[3];
    const float* b_f    = (const float*)d_in[4];
    const float* W_ih_r = (const float*)d_in[5];
    const float* W_hh_r = (const float*)d_in[6];
    const float* b_r    = (const float*)d_in[7];
    const float* W_fc   = (const float*)d_in[8];
    const float* b_fc   = (const float*)d_in[9];
    float* out = (float*)d_out;

    float* ws     = (float*)d_ws;
    float* WihT_f = ws;                        // 131072 f
    float* WihT_r = WihT_f + 131072;           // 131072 f
    float* WfcT   = WihT_r + 131072;           // 65536 f
    float* mask_t = WfcT + 65536;              // 65536 f
    float* xWP_f  = mask_t + 65536;            // 2097152 f
    float* xWP_r  = xWP_f + 2097152;           // 2097152 f
    float* yb     = xWP_r + 2097152;           // 1048576 f
    short* Wp_f   = (short*)(yb + 1048576);    // 262144 bf16
    short* Wp_r   = Wp_f + 262144;             // 262144 bf16

    prep_k<<<456, dim3(32, 8), 0, stream>>>(
        W_ih_f, W_ih_r, W_hh_f, W_hh_r, W_fc, mask,
        WihT_f, WihT_r, WfcT, mask_t, Wp_f, Wp_r);

    k1_xw<<<128, 512, 0, stream>>>(x, WihT_f, WihT_r, xWP_f, xWP_r);
    k2_lstm<<<256, 1024, 0, stream>>>(mask_t, xWP_f, xWP_r, Wp_f, Wp_r, b_f, b_r, yb);
    k3_out<<<64, 256, 0, stream>>>(yb, WfcT, b_fc, out);
}

// Round 6
// 250.337 us; speedup vs baseline: 2.5208x; 1.2178x over previous
//
#include <hip/hip_runtime.h>
#include <math.h>

// Problem constants
constexpr int kB    = 64;
constexpr int kN    = 32;
constexpr int kDIN  = 128;
constexpr int kH    = 256;
constexpr int kG4   = 1024;   // 4*H
constexpr int kDOUT = 128;
constexpr int kBN   = 2048;   // B*N

typedef __attribute__((ext_vector_type(8))) short bf16x8;
typedef __attribute__((ext_vector_type(4))) float f32x4;

// fast sigmoid/tanh: v_exp_f32 + v_rcp_f32 (1-2 ulp, far below bf16-h noise)
__device__ __forceinline__ float sigm(float x) {
    return __builtin_amdgcn_rcpf(1.0f + __expf(-x));
}
__device__ __forceinline__ float tanh_f(float x) {
    return 1.0f - 2.0f * __builtin_amdgcn_rcpf(1.0f + __expf(2.0f * x));
}

// fp32 -> bf16 bits, round-to-nearest-even
__device__ __forceinline__ short f2bf(float f) {
    union { float f; unsigned u; } v; v.f = f;
    unsigned r = v.u + 0x7fffu + ((v.u >> 16) & 1u);
    return (short)(r >> 16);
}

// ---------------------------------------------------------------------------
// prep:
//   [0,128)   transpose W_ih_f (1024x128) -> WihT_f [k][gate]
//   [128,256) transpose W_ih_r            -> WihT_r
//   [256,320) transpose W_fc   (128x512)  -> WfcT   [k][dout]
//   [320,448) pack W_hh (bf16) into per-wave MFMA fragment order:
//             Wp[((wv*8+kt)*8+tau)*512 + lane*8 + j]
//               = W_hh[(tau>>1)*256 + wv*32 + (tau&1)*16 + l15][kt*32+quad*8+j]
//   [448,456) transpose mask -> mask_t [n][t][b]
// ---------------------------------------------------------------------------
__global__ __launch_bounds__(256) void prep_k(
    const float* __restrict__ Wihf, const float* __restrict__ Wihr,
    const float* __restrict__ Whhf, const float* __restrict__ Whhr,
    const float* __restrict__ Wfc,  const float* __restrict__ mask,
    float* __restrict__ WihTf, float* __restrict__ WihTr,
    float* __restrict__ WfcT,  float* __restrict__ mask_t,
    short* __restrict__ Wp_f,  short* __restrict__ Wp_r)
{
    const int bx  = blockIdx.x;
    const int tid = threadIdx.y * 32 + threadIdx.x;

    if (bx >= 448) {                       // mask transpose: [b][n][t] -> [n][t][b]
        const int base = (bx - 448) * 8192 + tid;
        #pragma unroll
        for (int i = 0; i < 32; ++i) {
            const int idx = base + i * 256;
            const int n = idx >> 11, tt = (idx >> 6) & 31, b = idx & 63;
            mask_t[idx] = mask[(size_t)b * 1024 + n * 32 + tt];
        }
        return;
    }
    if (bx >= 320) {                       // W_hh fragment pack
        const int idx = bx - 320;
        const int dir = idx >> 6;
        const int wv  = (idx >> 3) & 7;
        const int kt  = idx & 7;
        const float* src = dir ? Whhr : Whhf;
        short* dst = (dir ? Wp_r : Wp_f) + (size_t)((wv * 8 + kt) * 8) * 512;
        for (int i = tid; i < 512; i += 256) {
            const int tau = i >> 6, lane = i & 63;
            const int qd = lane >> 4, l = lane & 15;
            const int gate = (tau >> 1) * 256 + wv * 32 + (tau & 1) * 16 + l;
            const int ks = kt * 32 + qd * 8;
            bf16x8 v;
            #pragma unroll
            for (int j = 0; j < 8; ++j) v[j] = f2bf(src[(size_t)gate * kH + ks + j]);
            *(bf16x8*)(dst + tau * 512 + lane * 8) = v;
        }
        return;
    }
    __shared__ float tile[32][33];
    const float* src; float* dst; int R, C, t;
    if (bx < 128)      { src = Wihf; dst = WihTf; R = 1024; C = 128; t = bx; }
    else if (bx < 256) { src = Wihr; dst = WihTr; R = 1024; C = 128; t = bx - 128; }
    else               { src = Wfc;  dst = WfcT;  R = 128;  C = 512; t = bx - 256; }
    const int tilesX = C / 32;
    const int c0 = (t % tilesX) * 32;
    const int r0 = (t / tilesX) * 32;
    const int tx = threadIdx.x, ty = threadIdx.y;
    #pragma unroll
    for (int i = ty; i < 32; i += 8)
        tile[i][tx] = src[(size_t)(r0 + i) * C + (c0 + tx)];
    __syncthreads();
    #pragma unroll
    for (int i = ty; i < 32; i += 8)
        dst[(size_t)(c0 + i) * R + (r0 + tx)] = tile[tx][i];
}

// ---------------------------------------------------------------------------
// k1: xW = x @ W_ih.T, written in k2's packed-fragment layout (M=16 tiles):
//   xWP[(t*4+bq4)*4096 + wg*512 + taug*64 + qd*16 + l15]  (f32x4 over r)
// Grid 128 = dir(2) x t(32) x bq(2: 32 rows). 512 thr; 8-row x 8-gate reg tile.
// waves_per_eu(2,2): pin 256-reg budget (live set ~140 regs; default 128-reg
// target would spill -- same allocator-heuristic disease as k2 rounds 4/5).
// ---------------------------------------------------------------------------
__global__ __launch_bounds__(512)
__attribute__((amdgpu_waves_per_eu(2, 2))) void k1_xw(
    const float* __restrict__ x,
    const float* __restrict__ WihT_f, const float* __restrict__ WihT_r,
    float* __restrict__ xWP_f, float* __restrict__ xWP_r)
{
    __shared__ float xs[32][128];               // 16 KB
    const int tid  = threadIdx.x;
    const int bx   = blockIdx.x;
    const int dir  = bx >> 6;
    const int rest = bx & 63;
    const int t    = rest >> 1;
    const int bq   = rest & 1;                  // 32-batch half
    const float* __restrict__ WT = dir ? WihT_r : WihT_f;
    float* __restrict__ xWP = dir ? xWP_r : xWP_f;

    for (int i = tid; i < 1024; i += 512) {
        const int rr = i >> 5, c4 = i & 31;
        *(f32x4*)&xs[rr][c4 * 4] =
            *(const f32x4*)&x[((size_t)(bq * 32 + rr) * 32 + t) * 128 + c4 * 4];
    }
    __syncthreads();

    const int rowg = tid >> 7;    // 0..3 -> rows rowg*8..+7
    const int gg   = tid & 127;   // gates {gg*4+j} and {512+gg*4+j}

    float acc0[8][4], acc1[8][4];
    #pragma unroll
    for (int r = 0; r < 8; ++r)
        #pragma unroll
        for (int j = 0; j < 4; ++j) { acc0[r][j] = 0.f; acc1[r][j] = 0.f; }

    for (int k4 = 0; k4 < 32; ++k4) {
        f32x4 w0[4], w1[4], xv[8];
        #pragma unroll
        for (int kk = 0; kk < 4; ++kk) {
            w0[kk] = *(const f32x4*)&WT[(size_t)(k4 * 4 + kk) * 1024 + gg * 4];
            w1[kk] = *(const f32x4*)&WT[(size_t)(k4 * 4 + kk) * 1024 + 512 + gg * 4];
        }
        #pragma unroll
        for (int r = 0; r < 8; ++r) xv[r] = *(const f32x4*)&xs[rowg * 8 + r][k4 * 4];
        #pragma unroll
        for (int r = 0; r < 8; ++r)
            #pragma unroll
            for (int kk = 0; kk < 4; ++kk) {
                const float xk = xv[r][kk];
                #pragma unroll
                for (int j = 0; j < 4; ++j) {
                    acc0[r][j] = fmaf(xk, w0[kk][j], acc0[r][j]);
                    acc1[r][j] = fmaf(xk, w1[kk][j], acc1[r][j]);
                }
            }
    }

    #pragma unroll
    for (int hf = 0; hf < 2; ++hf)
        #pragma unroll
        for (int j = 0; j < 4; ++j) {
            const int g    = hf * 512 + gg * 4 + j;
            const int l15g = g & 15;
            const int qg   = (g >> 4) & 1;
            const int wg   = (g >> 5) & 7;
            const int taug = (g >> 8) * 2 + qg;
            #pragma unroll
            for (int p = 0; p < 2; ++p) {
                const int b   = bq * 32 + rowg * 8 + p * 4;   // +r in vector
                const int bq4 = b >> 4;
                const int qd  = (b >> 2) & 3;
                f32x4 v;
                #pragma unroll
                for (int r = 0; r < 4; ++r)
                    v[r] = hf ? acc1[p * 4 + r][j] : acc0[p * 4 + r][j];
                ((f32x4*)xWP)[(size_t)(t * 4 + bq4) * 4096 + wg * 512 + taug * 64
                              + qd * 16 + l15g] = v;
            }
        }
}

// ---------------------------------------------------------------------------
// k2: bidirectional LSTM recurrence, bf16 MFMA fp32 accumulate.
// Grid 256 = dir(2) x n(32) x bq(4: 16 batches). 1024 thr = 16 waves, M=16.
// Three-tier W split (W/dir = 512 KB):
//   kt 0..3: persisted in VGPRs (64 regs/thread)
//   kt 4..5: parked in LDS once (128 KB; wave-private slices, no barriers)
//   kt 6..7: streamed per step from L2-resident packed Wp (128 KB/step)
// ROUND-6 FIXES (counters showed ~54 regs/thread spilled, VGPR_Count=64):
//   (1) amdgpu_waves_per_eu(4,4): LDS caps CU at 1 block = 4 waves/EU anyway;
//       pin the allocator there -> full 128-reg budget, no spill-for-occupancy.
//   (2) opaque-zero (asm) added to tier-2/3 addresses each step: blocks LICM
//       from hoisting those loop-invariant loads into +64 registers.
// One-step-deep register prefetch of packed xW+mask retained.
// ---------------------------------------------------------------------------
__global__ __launch_bounds__(1024)
__attribute__((amdgpu_waves_per_eu(4, 4))) void k2_lstm(
    const float* __restrict__ mask_t,
    const float* __restrict__ xWP_f, const float* __restrict__ xWP_r,
    const short* __restrict__ Wp_f, const short* __restrict__ Wp_r,
    const float* __restrict__ b_f,  const float* __restrict__ b_r,
    float* __restrict__ y)
{
    constexpr int HP = 272;
    __shared__ short h_lds[2][16][HP];          // 17408 B
    __shared__ short w_lds[16][8][512];         // 131072 B: kt=4,5 x 4g per wave

    const int tid  = threadIdx.x;
    const int w    = tid >> 6;                  // 0..15
    const int lane = tid & 63;
    const int quad = lane >> 4;
    const int l15  = lane & 15;

    const int bx    = blockIdx.x;
    const int dir   = bx >> 7;                  // 0 fwd, 1 rev
    const int rest  = bx & 127;
    const int n_seq = rest >> 2;                // 0..31
    const int bq    = rest & 3;                 // batch quarter (16 each)

    const float* __restrict__ xWP = dir ? xWP_r : xWP_f;
    const short* __restrict__ Wp  = dir ? Wp_r  : Wp_f;
    const float* __restrict__ bb  = dir ? b_r   : b_f;

    // wave w <-> packed layout: wv = w>>1, tau = g*2 + (w&1)
    const int wv = w >> 1;
    const int wo = w & 1;

    float bias[4];
    #pragma unroll
    for (int g = 0; g < 4; ++g)
        bias[g] = bb[g * 256 + w * 16 + l15];

    // tier 1: persist kt = 0..3 in registers (64 VGPRs)
    bf16x8 wreg[4][4];
    #pragma unroll
    for (int kt = 0; kt < 4; ++kt)
        #pragma unroll
        for (int g = 0; g < 4; ++g)
            wreg[kt][g] = *(const bf16x8*)(
                Wp + (size_t)((wv * 8 + kt) * 8 + g * 2 + wo) * 512 + lane * 8);

    // tier 2: park kt = 4..5 in this wave's private LDS stash.
    #pragma unroll
    for (int f = 0; f < 8; ++f) {
        const int kt = 4 + (f >> 2), g = f & 3;
        *(bf16x8*)&w_lds[w][f][lane * 8] = *(const bf16x8*)(
            Wp + (size_t)((wv * 8 + kt) * 8 + g * 2 + wo) * 512 + lane * 8);
    }

    float c[4];
    #pragma unroll
    for (int i = 0; i < 4; ++i) c[i] = 0.f;

    const int nsteps = dir ? (kN - n_seq) : (n_seq + 1);
    const int t0     = dir ? (kN - 1) : 0;

    // per-wave xW base: (t*4+bq)*4096 + wv*512 + wo*64 + lane; +g*128
    const f32x4* xWPv = (const f32x4*)xWP + (wv * 512 + wo * 64 + lane);

    // initial prefetch of packed xW + mask for t0
    f32x4 xwn[4];
    f32x4 mkn;
    {
        const f32x4* xb4 = xWPv + (size_t)(t0 * 4 + bq) * 4096;
        #pragma unroll
        for (int g = 0; g < 4; ++g) xwn[g] = xb4[g * 128];
        mkn = ((const f32x4*)mask_t)[(n_seq * 32 + t0) * 16 + bq * 4 + quad];
    }

    int zro = 0;                  // opaque 0: blocks LICM of tier-2/3 loads

    int cur = 0;
    for (int it = 0; it < nsteps; ++it) {
        const int t = dir ? (kN - 1 - it) : it;

        asm volatile("" : "+v"(zro));   // redefine each step -> loop-variant

        // consume prefetched xW/mask into acc
        f32x4 acc[4];
        #pragma unroll
        for (int g = 0; g < 4; ++g)
            #pragma unroll
            for (int r = 0; r < 4; ++r)
                acc[g][r] = fmaf(mkn[r], xwn[g][r], bias[g]);

        // prefetch next step's xW/mask (overlaps K-loop + epilogue + barrier)
        {
            const int tn = (it + 1 < nsteps) ? (dir ? t - 1 : t + 1) : t;
            const f32x4* xb4 = xWPv + (size_t)(tn * 4 + bq) * 4096;
            #pragma unroll
            for (int g = 0; g < 4; ++g) xwn[g] = xb4[g * 128];
            mkn = ((const f32x4*)mask_t)[(n_seq * 32 + tn) * 16 + bq * 4 + quad];
        }

        // K loop: kt 0..3 regs, kt 4..5 LDS stash, kt 6..7 streamed from L2
        if (it > 0) {
            #pragma unroll
            for (int kt = 0; kt < 4; ++kt) {
                const bf16x8 a = *(const bf16x8*)&h_lds[cur][l15][kt * 32 + quad * 8];
                #pragma unroll
                for (int g = 0; g < 4; ++g)
                    acc[g] = __builtin_amdgcn_mfma_f32_16x16x32_bf16(
                        a, wreg[kt][g], acc[g], 0, 0, 0);
            }
            #pragma unroll
            for (int kk = 0; kk < 2; ++kk) {
                const int kt = 4 + kk;
                const bf16x8 a = *(const bf16x8*)&h_lds[cur][l15][kt * 32 + quad * 8];
                #pragma unroll
                for (int g = 0; g < 4; ++g) {
                    const bf16x8 wf = *(const bf16x8*)&w_lds[w][kk * 4 + g][lane * 8 + zro];
                    acc[g] = __builtin_amdgcn_mfma_f32_16x16x32_bf16(
                        a, wf, acc[g], 0, 0, 0);
                }
            }
            #pragma unroll
            for (int kk = 0; kk < 2; ++kk) {
                const int kt = 6 + kk;
                const bf16x8 a = *(const bf16x8*)&h_lds[cur][l15][kt * 32 + quad * 8];
                #pragma unroll
                for (int g = 0; g < 4; ++g) {
                    const bf16x8 wf = *(const bf16x8*)(
                        Wp + (size_t)((wv * 8 + kt) * 8 + g * 2 + wo) * 512
                           + lane * 8 + zro);
                    acc[g] = __builtin_amdgcn_mfma_f32_16x16x32_bf16(
                        a, wf, acc[g], 0, 0, 0);
                }
            }
        }

        // epilogue: lane owns unit u = w*16+l15, rows m = quad*4+r
        const int nxt = cur ^ 1;
        const int u = w * 16 + l15;
        #pragma unroll
        for (int r = 0; r < 4; ++r) {
            const float gI = acc[0][r];
            const float gF = acc[1][r];
            const float gG = acc[2][r];
            const float gO = acc[3][r];
            const float ct = sigm(gF) * c[r] + sigm(gI) * tanh_f(gG);
            c[r] = ct;
            const float hn = sigm(gO) * tanh_f(ct);
            const int m = quad * 4 + r;
            h_lds[nxt][m][u] = f2bf(hn);
            if (it == nsteps - 1)
                y[((size_t)(bq * 16 + m) * kN + n_seq) * (2 * kH)
                  + dir * kH + u] = hn;
        }
        if (it + 1 < nsteps) __syncthreads();
        cur = nxt;
    }
}

// ---------------------------------------------------------------------------
// k3: out = relu(y @ W_fc.T + b_fc). 64 blocks x 32 rows; 256 thr;
// 4x4 register tile; W_fc streamed once per 32 rows (16 MB total).
// ---------------------------------------------------------------------------
__global__ __launch_bounds__(256) void k3_out(
    const float* __restrict__ y, const float* __restrict__ WfcT,
    const float* __restrict__ b_fc, float* __restrict__ out)
{
    __shared__ float ys[32][512];               // 64 KB
    const int tid = threadIdx.x;
    const int r0  = blockIdx.x * 32;
    for (int i = tid; i < 4096; i += 256)
        ((f32x4*)ys)[i] = ((const f32x4*)(y + (size_t)r0 * 512))[i];
    __syncthreads();

    const int rowg = tid >> 5;                  // 0..7 -> rows rowg*4..+3
    const int cg   = tid & 31;                  // cols cg*4..+3

    f32x4 acc[4];
    #pragma unroll
    for (int r = 0; r < 4; ++r) acc[r] = (f32x4){0.f, 0.f, 0.f, 0.f};

    #pragma unroll 4
    for (int k = 0; k < 512; ++k) {
        const f32x4 wv = *(const f32x4*)&WfcT[(size_t)k * 128 + cg * 4];
        #pragma unroll
        for (int r = 0; r < 4; ++r) {
            const float yv = ys[rowg * 4 + r][k];
            #pragma unroll
            for (int j = 0; j < 4; ++j)
                acc[r][j] = fmaf(yv, wv[j], acc[r][j]);
        }
    }

    const f32x4 bv = *(const f32x4*)&b_fc[cg * 4];
    #pragma unroll
    for (int r = 0; r < 4; ++r) {
        f32x4 o;
        #pragma unroll
        for (int j = 0; j < 4; ++j) o[j] = fmaxf(acc[r][j] + bv[j], 0.f);
        *(f32x4*)&out[(size_t)(r0 + rowg * 4 + r) * 128 + cg * 4] = o;
    }
}

// ---------------------------------------------------------------------------
extern "C" void kernel_launch(void* const* d_in, const int* in_sizes, int n_in,
                              void* d_out, int out_size, void* d_ws, size_t ws_size,
                              hipStream_t stream) {
    const float* x      = (const float*)d_in[0];
    const float* mask   = (const float*)d_in[1];
    const float* W_ih_f = (const float*)d_in[2];
    const float* W_hh_f = (const float*)d_in[3];
    const float* b_f    = (const float*)d_in[4];
    const float* W_ih_r = (const float*)d_in[5];
    const float* W_hh_r = (const float*)d_in[6];
    const float* b_r    = (const float*)d_in[7];
    const float* W_fc   = (const float*)d_in[8];
    const float* b_fc   = (const float*)d_in[9];
    float* out = (float*)d_out;

    float* ws     = (float*)d_ws;
    float* WihT_f = ws;                        // 131072 f
    float* WihT_r = WihT_f + 131072;           // 131072 f
    float* WfcT   = WihT_r + 131072;           // 65536 f
    float* mask_t = WfcT + 65536;              // 65536 f
    float* xWP_f  = mask_t + 65536;            // 2097152 f
    float* xWP_r  = xWP_f + 2097152;           // 2097152 f
    float* yb     = xWP_r + 2097152;           // 1048576 f
    short* Wp_f   = (short*)(yb + 1048576);    // 262144 bf16
    short* Wp_r   = Wp_f + 262144;             // 262144 bf16

    prep_k<<<456, dim3(32, 8), 0, stream>>>(
        W_ih_f, W_ih_r, W_hh_f, W_hh_r, W_fc, mask,
        WihT_f, WihT_r, WfcT, mask_t, Wp_f, Wp_r);

    k1_xw<<<128, 512, 0, stream>>>(x, WihT_f, WihT_r, xWP_f, xWP_r);
    k2_lstm<<<256, 1024, 0, stream>>>(mask_t, xWP_f, xWP_r, Wp_f, Wp_r, b_f, b_r, yb);
    k3_out<<<64, 256, 0, stream>>>(yb, WfcT, b_fc, out);
}

// Round 7
// 190.756 us; speedup vs baseline: 3.3081x; 1.3123x over previous
//
#include <hip/hip_runtime.h>
#include <math.h>

// Problem constants
constexpr int kB    = 64;
constexpr int kN    = 32;
constexpr int kDIN  = 128;
constexpr int kH    = 256;
constexpr int kG4   = 1024;   // 4*H
constexpr int kDOUT = 128;
constexpr int kBN   = 2048;   // B*N

typedef __attribute__((ext_vector_type(8))) short bf16x8;
typedef __attribute__((ext_vector_type(4))) float f32x4;

// fast sigmoid/tanh: v_exp_f32 + v_rcp_f32 (1-2 ulp, far below bf16-h noise)
__device__ __forceinline__ float sigm(float x) {
    return __builtin_amdgcn_rcpf(1.0f + __expf(-x));
}
__device__ __forceinline__ float tanh_f(float x) {
    return 1.0f - 2.0f * __builtin_amdgcn_rcpf(1.0f + __expf(2.0f * x));
}

// fp32 -> bf16 bits, round-to-nearest-even
__device__ __forceinline__ short f2bf(float f) {
    union { float f; unsigned u; } v; v.f = f;
    unsigned r = v.u + 0x7fffu + ((v.u >> 16) & 1u);
    return (short)(r >> 16);
}
__device__ __forceinline__ float bf2f(short h) {
    union { unsigned u; float f; } v; v.u = ((unsigned)(unsigned short)h) << 16;
    return v.f;
}
// fp32 -> (hi, lo) bf16 pair: hi + lo ~ f with ~2^-17 relative error
__device__ __forceinline__ void split_bf(float f, short& hi, short& lo) {
    const short h = f2bf(f);
    hi = h;
    lo = f2bf(f - bf2f(h));
}
// two f32x4 -> hi/lo bf16x8 fragments
__device__ __forceinline__ void cvt8(const f32x4 a, const f32x4 b,
                                     bf16x8& hi, bf16x8& lo) {
    #pragma unroll
    for (int j = 0; j < 4; ++j) { short h, l; split_bf(a[j], h, l); hi[j] = h; lo[j] = l; }
    #pragma unroll
    for (int j = 0; j < 4; ++j) { short h, l; split_bf(b[j], h, l); hi[4 + j] = h; lo[4 + j] = l; }
}

// ---------------------------------------------------------------------------
// prep (272 blocks x 256 thr):
//   [0,128)   pack W_hh (bf16) into k2's per-wave MFMA fragment order:
//             Wp[((wv*8+kt)*8+tau)*512 + lane*8 + j]
//               = W_hh[(tau>>1)*256 + wv*32 + (tau&1)*16 + l15][kt*32+quad*8+j]
//   [128,256) pack W_ih hi/lo (fp32->bf16 pair) fragment-contiguous:
//             Wih?[(ng*4+kt)*512 + lane*8 + j]
//               = split(W_ih[ng*16+l15][kt*32+quad*8+j])
//   [256,264) pack W_fc hi/lo: Wfc?[(ng*16+kt)*512 + lane*8 + j]
//               = split(W_fc[ng*16+l15][kt*32+quad*8+j])
//   [264,272) transpose mask -> mask_t [n][t][b]
// (No fp32 transposes needed anymore: MFMA B wants original [gate][k] order.)
// ---------------------------------------------------------------------------
__global__ __launch_bounds__(256) void prep_k(
    const float* __restrict__ Wihf, const float* __restrict__ Wihr,
    const float* __restrict__ Whhf, const float* __restrict__ Whhr,
    const float* __restrict__ Wfc,  const float* __restrict__ mask,
    float* __restrict__ mask_t,
    short* __restrict__ Wp_f,  short* __restrict__ Wp_r,
    short* __restrict__ Wihh_f, short* __restrict__ Wihl_f,
    short* __restrict__ Wihh_r, short* __restrict__ Wihl_r,
    short* __restrict__ Wfch,   short* __restrict__ Wfcl)
{
    const int bx  = blockIdx.x;
    const int tid = threadIdx.y * 32 + threadIdx.x;

    if (bx < 128) {                        // W_hh fragment pack (bf16, k2)
        const int idx = bx;
        const int dir = idx >> 6;
        const int wv  = (idx >> 3) & 7;
        const int kt  = idx & 7;
        const float* src = dir ? Whhr : Whhf;
        short* dst = (dir ? Wp_r : Wp_f) + (size_t)((wv * 8 + kt) * 8) * 512;
        for (int i = tid; i < 512; i += 256) {
            const int tau = i >> 6, lane = i & 63;
            const int qd = lane >> 4, l = lane & 15;
            const int gate = (tau >> 1) * 256 + wv * 32 + (tau & 1) * 16 + l;
            const int ks = kt * 32 + qd * 8;
            bf16x8 v;
            #pragma unroll
            for (int j = 0; j < 8; ++j) v[j] = f2bf(src[(size_t)gate * kH + ks + j]);
            *(bf16x8*)(dst + tau * 512 + lane * 8) = v;
        }
        return;
    }
    if (bx < 256) {                        // W_ih hi/lo fragment pack (k1)
        const int idx = bx - 128;
        const int dir = idx >> 6;
        const int ng  = idx & 63;
        const float* src = dir ? Wihr : Wihf;
        short* dh = (dir ? Wihh_r : Wihh_f);
        short* dl = (dir ? Wihl_r : Wihl_f);
        const int kt   = tid >> 6;
        const int lane = tid & 63;
        const int qd   = lane >> 4, l = lane & 15;
        const int ks   = kt * 32 + qd * 8;
        bf16x8 vh, vl;
        #pragma unroll
        for (int j = 0; j < 8; ++j) {
            short h, lo;
            split_bf(src[(size_t)(ng * 16 + l) * kDIN + ks + j], h, lo);
            vh[j] = h; vl[j] = lo;
        }
        const size_t off = (size_t)((ng * 4 + kt) * 64 + lane) * 8;
        *(bf16x8*)(dh + off) = vh;
        *(bf16x8*)(dl + off) = vl;
        return;
    }
    if (bx < 264) {                        // W_fc hi/lo fragment pack (k3)
        const int ng   = bx - 256;         // 0..7
        const int lane = tid & 63;
        const int qd   = lane >> 4, l = lane & 15;
        #pragma unroll
        for (int p = 0; p < 4; ++p) {
            const int kt = p * 4 + (tid >> 6);
            const int ks = kt * 32 + qd * 8;
            bf16x8 vh, vl;
            #pragma unroll
            for (int j = 0; j < 8; ++j) {
                short h, lo;
                split_bf(Wfc[(size_t)(ng * 16 + l) * (2 * kH) + ks + j], h, lo);
                vh[j] = h; vl[j] = lo;
            }
            const size_t off = (size_t)((ng * 16 + kt) * 64 + lane) * 8;
            *(bf16x8*)(Wfch + off) = vh;
            *(bf16x8*)(Wfcl + off) = vl;
        }
        return;
    }
    // mask transpose: [b][n][t] -> [n][t][b]
    const int base = (bx - 264) * 8192 + tid;
    #pragma unroll
    for (int i = 0; i < 32; ++i) {
        const int idx = base + i * 256;
        const int n = idx >> 11, tt = (idx >> 6) & 31, b = idx & 63;
        mask_t[idx] = mask[(size_t)b * 1024 + n * 32 + tt];
    }
}

// ---------------------------------------------------------------------------
// k1 (NEW: MFMA + fp32->hi/lo bf16 split; 3 MFMAs approximate fp32 product,
// error ~1e-5 << bf16-h noise). xW = x @ W_ih.T in k2's packed layout.
// Grid 256 = dir(2) x t(32) x nt(4: 256 gates). 256 thr = 4 waves.
// Block: 64 rows (all b at fixed t) x 256 gates. A-frags (x hi/lo) precomputed
// in regs (128 VGPRs -> waves_per_eu(1,1); grid is 1 block/CU anyway).
// 192 MFMAs/block; B streamed wave-contiguous from packed Wih hi/lo.
// ---------------------------------------------------------------------------
__global__ __launch_bounds__(256)
__attribute__((amdgpu_waves_per_eu(1, 1))) void k1_xw(
    const float* __restrict__ x,
    const short* __restrict__ Wihh_f, const short* __restrict__ Wihl_f,
    const short* __restrict__ Wihh_r, const short* __restrict__ Wihl_r,
    float* __restrict__ xWP_f, float* __restrict__ xWP_r)
{
    __shared__ float xs[64][128];               // 32 KB
    const int tid  = threadIdx.x;
    const int w    = tid >> 6;                  // wave 0..3
    const int lane = tid & 63;
    const int quad = lane >> 4;
    const int l15  = lane & 15;

    const int bx   = blockIdx.x;
    const int dir  = bx >> 7;
    const int rest = bx & 127;
    const int t    = rest >> 2;
    const int nt   = rest & 3;                  // 256-gate tile

    const short* __restrict__ Wh = dir ? Wihh_r : Wihh_f;
    const short* __restrict__ Wl = dir ? Wihl_r : Wihl_f;
    float* __restrict__ xWP = dir ? xWP_r : xWP_f;

    #pragma unroll
    for (int p = 0; p < 8; ++p) {
        const int idx = p * 256 + tid;
        const int row = idx >> 5, c4 = idx & 31;
        *(f32x4*)&xs[row][c4 * 4] =
            *(const f32x4*)&x[((size_t)row * 32 + t) * kDIN + c4 * 4];
    }
    __syncthreads();

    // A fragments: rows Mt*16+l15, k = kt*32+quad*8..+8, hi/lo
    bf16x8 ah[4][4], al[4][4];
    #pragma unroll
    for (int Mt = 0; Mt < 4; ++Mt)
        #pragma unroll
        for (int kt = 0; kt < 4; ++kt) {
            const f32x4 a0 = *(const f32x4*)&xs[Mt * 16 + l15][kt * 32 + quad * 8];
            const f32x4 a1 = *(const f32x4*)&xs[Mt * 16 + l15][kt * 32 + quad * 8 + 4];
            cvt8(a0, a1, ah[Mt][kt], al[Mt][kt]);
        }

    f32x4 acc[4][4];                            // [tau][Mt]
    #pragma unroll
    for (int tau = 0; tau < 4; ++tau)
        #pragma unroll
        for (int Mt = 0; Mt < 4; ++Mt) acc[tau][Mt] = (f32x4){0.f, 0.f, 0.f, 0.f};

    #pragma unroll
    for (int kt = 0; kt < 4; ++kt) {
        bf16x8 bh[4], bl[4];
        #pragma unroll
        for (int tau = 0; tau < 4; ++tau) {
            const int g16 = nt * 16 + w * 4 + tau;
            const size_t off = (size_t)((g16 * 4 + kt) * 64 + lane) * 8;
            bh[tau] = *(const bf16x8*)(Wh + off);
            bl[tau] = *(const bf16x8*)(Wl + off);
        }
        #pragma unroll
        for (int tau = 0; tau < 4; ++tau)
            #pragma unroll
            for (int Mt = 0; Mt < 4; ++Mt) {
                acc[tau][Mt] = __builtin_amdgcn_mfma_f32_16x16x32_bf16(
                    ah[Mt][kt], bh[tau], acc[tau][Mt], 0, 0, 0);
                acc[tau][Mt] = __builtin_amdgcn_mfma_f32_16x16x32_bf16(
                    ah[Mt][kt], bl[tau], acc[tau][Mt], 0, 0, 0);
                acc[tau][Mt] = __builtin_amdgcn_mfma_f32_16x16x32_bf16(
                    al[Mt][kt], bh[tau], acc[tau][Mt], 0, 0, 0);
            }
    }

    // store to packed xWP: row b = Mt*16 + quad*4 + r; gate = g16*16 + l15
    #pragma unroll
    for (int tau = 0; tau < 4; ++tau) {
        const int g16  = nt * 16 + w * 4 + tau;
        const int wg   = (g16 >> 1) & 7;
        const int taug = (g16 >> 4) * 2 + (g16 & 1);
        #pragma unroll
        for (int Mt = 0; Mt < 4; ++Mt)
            ((f32x4*)xWP)[(size_t)(t * 4 + Mt) * 4096 + wg * 512 + taug * 64
                          + quad * 16 + l15] = acc[tau][Mt];
    }
}

// ---------------------------------------------------------------------------
// k2: bidirectional LSTM recurrence (UNCHANGED from round 6; 103 us).
// ---------------------------------------------------------------------------
__global__ __launch_bounds__(1024)
__attribute__((amdgpu_waves_per_eu(4, 4))) void k2_lstm(
    const float* __restrict__ mask_t,
    const float* __restrict__ xWP_f, const float* __restrict__ xWP_r,
    const short* __restrict__ Wp_f, const short* __restrict__ Wp_r,
    const float* __restrict__ b_f,  const float* __restrict__ b_r,
    float* __restrict__ y)
{
    constexpr int HP = 272;
    __shared__ short h_lds[2][16][HP];          // 17408 B
    __shared__ short w_lds[16][8][512];         // 131072 B: kt=4,5 x 4g per wave

    const int tid  = threadIdx.x;
    const int w    = tid >> 6;                  // 0..15
    const int lane = tid & 63;
    const int quad = lane >> 4;
    const int l15  = lane & 15;

    const int bx    = blockIdx.x;
    const int dir   = bx >> 7;                  // 0 fwd, 1 rev
    const int rest  = bx & 127;
    const int n_seq = rest >> 2;                // 0..31
    const int bq    = rest & 3;                 // batch quarter (16 each)

    const float* __restrict__ xWP = dir ? xWP_r : xWP_f;
    const short* __restrict__ Wp  = dir ? Wp_r  : Wp_f;
    const float* __restrict__ bb  = dir ? b_r   : b_f;

    const int wv = w >> 1;
    const int wo = w & 1;

    float bias[4];
    #pragma unroll
    for (int g = 0; g < 4; ++g)
        bias[g] = bb[g * 256 + w * 16 + l15];

    // tier 1: persist kt = 0..3 in registers
    bf16x8 wreg[4][4];
    #pragma unroll
    for (int kt = 0; kt < 4; ++kt)
        #pragma unroll
        for (int g = 0; g < 4; ++g)
            wreg[kt][g] = *(const bf16x8*)(
                Wp + (size_t)((wv * 8 + kt) * 8 + g * 2 + wo) * 512 + lane * 8);

    // tier 2: park kt = 4..5 in this wave's private LDS stash.
    #pragma unroll
    for (int f = 0; f < 8; ++f) {
        const int kt = 4 + (f >> 2), g = f & 3;
        *(bf16x8*)&w_lds[w][f][lane * 8] = *(const bf16x8*)(
            Wp + (size_t)((wv * 8 + kt) * 8 + g * 2 + wo) * 512 + lane * 8);
    }

    float c[4];
    #pragma unroll
    for (int i = 0; i < 4; ++i) c[i] = 0.f;

    const int nsteps = dir ? (kN - n_seq) : (n_seq + 1);
    const int t0     = dir ? (kN - 1) : 0;

    const f32x4* xWPv = (const f32x4*)xWP + (wv * 512 + wo * 64 + lane);

    f32x4 xwn[4];
    f32x4 mkn;
    {
        const f32x4* xb4 = xWPv + (size_t)(t0 * 4 + bq) * 4096;
        #pragma unroll
        for (int g = 0; g < 4; ++g) xwn[g] = xb4[g * 128];
        mkn = ((const f32x4*)mask_t)[(n_seq * 32 + t0) * 16 + bq * 4 + quad];
    }

    int zro = 0;                  // opaque 0: blocks LICM of tier-2/3 loads

    int cur = 0;
    for (int it = 0; it < nsteps; ++it) {
        const int t = dir ? (kN - 1 - it) : it;

        asm volatile("" : "+v"(zro));   // redefine each step -> loop-variant

        f32x4 acc[4];
        #pragma unroll
        for (int g = 0; g < 4; ++g)
            #pragma unroll
            for (int r = 0; r < 4; ++r)
                acc[g][r] = fmaf(mkn[r], xwn[g][r], bias[g]);

        {
            const int tn = (it + 1 < nsteps) ? (dir ? t - 1 : t + 1) : t;
            const f32x4* xb4 = xWPv + (size_t)(tn * 4 + bq) * 4096;
            #pragma unroll
            for (int g = 0; g < 4; ++g) xwn[g] = xb4[g * 128];
            mkn = ((const f32x4*)mask_t)[(n_seq * 32 + tn) * 16 + bq * 4 + quad];
        }

        if (it > 0) {
            #pragma unroll
            for (int kt = 0; kt < 4; ++kt) {
                const bf16x8 a = *(const bf16x8*)&h_lds[cur][l15][kt * 32 + quad * 8];
                #pragma unroll
                for (int g = 0; g < 4; ++g)
                    acc[g] = __builtin_amdgcn_mfma_f32_16x16x32_bf16(
                        a, wreg[kt][g], acc[g], 0, 0, 0);
            }
            #pragma unroll
            for (int kk = 0; kk < 2; ++kk) {
                const int kt = 4 + kk;
                const bf16x8 a = *(const bf16x8*)&h_lds[cur][l15][kt * 32 + quad * 8];
                #pragma unroll
                for (int g = 0; g < 4; ++g) {
                    const bf16x8 wf = *(const bf16x8*)&w_lds[w][kk * 4 + g][lane * 8 + zro];
                    acc[g] = __builtin_amdgcn_mfma_f32_16x16x32_bf16(
                        a, wf, acc[g], 0, 0, 0);
                }
            }
            #pragma unroll
            for (int kk = 0; kk < 2; ++kk) {
                const int kt = 6 + kk;
                const bf16x8 a = *(const bf16x8*)&h_lds[cur][l15][kt * 32 + quad * 8];
                #pragma unroll
                for (int g = 0; g < 4; ++g) {
                    const bf16x8 wf = *(const bf16x8*)(
                        Wp + (size_t)((wv * 8 + kt) * 8 + g * 2 + wo) * 512
                           + lane * 8 + zro);
                    acc[g] = __builtin_amdgcn_mfma_f32_16x16x32_bf16(
                        a, wf, acc[g], 0, 0, 0);
                }
            }
        }

        const int nxt = cur ^ 1;
        const int u = w * 16 + l15;
        #pragma unroll
        for (int r = 0; r < 4; ++r) {
            const float gI = acc[0][r];
            const float gF = acc[1][r];
            const float gG = acc[2][r];
            const float gO = acc[3][r];
            const float ct = sigm(gF) * c[r] + sigm(gI) * tanh_f(gG);
            c[r] = ct;
            const float hn = sigm(gO) * tanh_f(ct);
            const int m = quad * 4 + r;
            h_lds[nxt][m][u] = f2bf(hn);
            if (it == nsteps - 1)
                y[((size_t)(bq * 16 + m) * kN + n_seq) * (2 * kH)
                  + dir * kH + u] = hn;
        }
        if (it + 1 < nsteps) __syncthreads();
        cur = nxt;
    }
}

// ---------------------------------------------------------------------------
// k3 (NEW: MFMA hi/lo split). out = relu(y @ W_fc.T + b_fc).
// Grid 128 blocks x 16 rows; 256 thr = 4 waves; wave owns 32 douts.
// K=512 in 16 kt steps; A (y) converted hi/lo per kt from LDS; B from packed
// Wfc hi/lo (wave-contiguous). 96 MFMAs/wave.
// ---------------------------------------------------------------------------
__global__ __launch_bounds__(256) void k3_out(
    const float* __restrict__ y,
    const short* __restrict__ Wfch, const short* __restrict__ Wfcl,
    const float* __restrict__ b_fc, float* __restrict__ out)
{
    __shared__ float ys[16][512];               // 32 KB
    const int tid  = threadIdx.x;
    const int w    = tid >> 6;
    const int lane = tid & 63;
    const int quad = lane >> 4;
    const int l15  = lane & 15;
    const int r0   = blockIdx.x * 16;

    #pragma unroll
    for (int p = 0; p < 8; ++p) {
        const int idx = p * 256 + tid;
        const int row = idx >> 7, c4 = idx & 127;
        *(f32x4*)&ys[row][c4 * 4] =
            *(const f32x4*)&y[(size_t)(r0 + row) * (2 * kH) + c4 * 4];
    }
    __syncthreads();

    f32x4 acc[2];
    acc[0] = (f32x4){0.f, 0.f, 0.f, 0.f};
    acc[1] = (f32x4){0.f, 0.f, 0.f, 0.f};

    #pragma unroll
    for (int kt = 0; kt < 16; ++kt) {
        const f32x4 a0 = *(const f32x4*)&ys[l15][kt * 32 + quad * 8];
        const f32x4 a1 = *(const f32x4*)&ys[l15][kt * 32 + quad * 8 + 4];
        bf16x8 ah, al;
        cvt8(a0, a1, ah, al);
        #pragma unroll
        for (int tau = 0; tau < 2; ++tau) {
            const int ng = w * 2 + tau;
            const size_t off = (size_t)((ng * 16 + kt) * 64 + lane) * 8;
            const bf16x8 bh = *(const bf16x8*)(Wfch + off);
            const bf16x8 bl = *(const bf16x8*)(Wfcl + off);
            acc[tau] = __builtin_amdgcn_mfma_f32_16x16x32_bf16(ah, bh, acc[tau], 0, 0, 0);
            acc[tau] = __builtin_amdgcn_mfma_f32_16x16x32_bf16(ah, bl, acc[tau], 0, 0, 0);
            acc[tau] = __builtin_amdgcn_mfma_f32_16x16x32_bf16(al, bh, acc[tau], 0, 0, 0);
        }
    }

    #pragma unroll
    for (int tau = 0; tau < 2; ++tau) {
        const int dout = (w * 2 + tau) * 16 + l15;
        const float bias = b_fc[dout];
        #pragma unroll
        for (int r = 0; r < 4; ++r)
            out[(size_t)(r0 + quad * 4 + r) * kDOUT + dout] =
                fmaxf(acc[tau][r] + bias, 0.f);
    }
}

// ---------------------------------------------------------------------------
extern "C" void kernel_launch(void* const* d_in, const int* in_sizes, int n_in,
                              void* d_out, int out_size, void* d_ws, size_t ws_size,
                              hipStream_t stream) {
    const float* x      = (const float*)d_in[0];
    const float* mask   = (const float*)d_in[1];
    const float* W_ih_f = (const float*)d_in[2];
    const float* W_hh_f = (const float*)d_in[3];
    const float* b_f    = (const float*)d_in[4];
    const float* W_ih_r = (const float*)d_in[5];
    const float* W_hh_r = (const float*)d_in[6];
    const float* b_r    = (const float*)d_in[7];
    const float* W_fc   = (const float*)d_in[8];
    const float* b_fc   = (const float*)d_in[9];
    float* out = (float*)d_out;

    float* ws     = (float*)d_ws;
    float* mask_t = ws;                        // 65536 f
    float* xWP_f  = mask_t + 65536;            // 2097152 f
    float* xWP_r  = xWP_f + 2097152;           // 2097152 f
    float* yb     = xWP_r + 2097152;           // 1048576 f
    short* Wp_f   = (short*)(yb + 1048576);    // 262144 bf16
    short* Wp_r   = Wp_f + 262144;             // 262144 bf16
    short* Wihh_f = Wp_r + 262144;             // 131072 bf16
    short* Wihl_f = Wihh_f + 131072;           // 131072 bf16
    short* Wihh_r = Wihl_f + 131072;           // 131072 bf16
    short* Wihl_r = Wihh_r + 131072;           // 131072 bf16
    short* Wfch   = Wihl_r + 131072;           // 65536 bf16
    short* Wfcl   = Wfch + 65536;              // 65536 bf16

    prep_k<<<272, dim3(32, 8), 0, stream>>>(
        W_ih_f, W_ih_r, W_hh_f, W_hh_r, W_fc, mask,
        mask_t, Wp_f, Wp_r, Wihh_f, Wihl_f, Wihh_r, Wihl_r, Wfch, Wfcl);

    k1_xw<<<256, 256, 0, stream>>>(x, Wihh_f, Wihl_f, Wihh_r, Wihl_r,
                                   xWP_f, xWP_r);
    k2_lstm<<<256, 1024, 0, stream>>>(mask_t, xWP_f, xWP_r, Wp_f, Wp_r,
                                      b_f, b_r, yb);
    k3_out<<<128, 256, 0, stream>>>(yb, Wfch, Wfcl, b_fc, out);
}